// Round 7
// baseline (306.488 us; speedup 1.0000x reference)
//
#include <hip/hip_runtime.h>

#define NN 50000
#define NE 400000

typedef __attribute__((ext_vector_type(8))) short short8v;
typedef __attribute__((ext_vector_type(4))) float f32x4;

__device__ __forceinline__ unsigned short f2bf_rtn(float x) {
    unsigned u = __float_as_uint(x);
    unsigned r = u + 0x7FFFu + ((u >> 16) & 1u);
    return (unsigned short)(r >> 16);
}
__device__ __forceinline__ float bf2f(unsigned short h) {
    return __uint_as_float(((unsigned)h) << 16);
}

// ---------------- prep: zero counts+cursor, convert all weights ----------------
// blocks 0..390: zero 100096 ints; 391..550: W1->w1t (N=320,KP=128,Kreal=109);
// 551..630: W2->w2t (N=64,KP=320); 631..646: [Wmu|Wls]->wct (64x64)
__global__ void prep_kernel(const float* __restrict__ W1, const float* __restrict__ W2,
                            const float* __restrict__ Wmu, const float* __restrict__ Wls,
                            int* __restrict__ zero_base,
                            unsigned short* __restrict__ w1t_hi, unsigned short* __restrict__ w1t_lo,
                            unsigned short* __restrict__ w2t_hi, unsigned short* __restrict__ w2t_lo,
                            unsigned short* __restrict__ wct_hi, unsigned short* __restrict__ wct_lo) {
    int b = blockIdx.x, tid = threadIdx.x;
    if (b < 391) {
        int i = b * 256 + tid;
        if (i < 100096) zero_base[i] = 0;
    } else if (b < 551) {
        int idx = (b - 391) * 256 + tid;  // < 40960
        int n = idx >> 7, k = idx & 127;
        float v = (k < 109) ? W1[(long)k * 320 + n] : 0.0f;
        unsigned short hb = f2bf_rtn(v);
        w1t_hi[idx] = hb;
        w1t_lo[idx] = f2bf_rtn(v - bf2f(hb));
    } else if (b < 631) {
        int idx = (b - 551) * 256 + tid;  // < 20480
        int n = idx / 320, k = idx - n * 320;
        float v = W2[(long)k * 64 + n];
        unsigned short hb = f2bf_rtn(v);
        w2t_hi[idx] = hb;
        w2t_lo[idx] = f2bf_rtn(v - bf2f(hb));
    } else {
        int idx = (b - 631) * 256 + tid;  // < 4096
        int n = idx >> 6, k = idx & 63;
        float v = (n < 32) ? Wmu[k * 32 + n] : Wls[k * 32 + (n - 32)];
        unsigned short hb = f2bf_rtn(v);
        wct_hi[idx] = hb;
        wct_lo[idx] = f2bf_rtn(v - bf2f(hb));
    }
}

__global__ void hist_kernel(const int* __restrict__ dst, int* __restrict__ counts) {
    for (int e = blockIdx.x * blockDim.x + threadIdx.x; e < NE; e += gridDim.x * blockDim.x)
        atomicAdd(&counts[dst[e]], 1);
}

// dinv + block-local exclusive scan (bsum = per-block total)
__global__ void dinv_scan1_kernel(const int* __restrict__ counts, float* __restrict__ dinv,
                                  int* __restrict__ rowstart, int* __restrict__ bsum) {
    __shared__ int tmp[256];
    int tid = threadIdx.x;
    int i = blockIdx.x * 256 + tid;
    int v = (i < NN) ? counts[i] : 0;
    if (i < NN) dinv[i] = rsqrtf((float)(v + 1));  // +1 self loop
    tmp[tid] = v;
    __syncthreads();
    for (int off = 1; off < 256; off <<= 1) {
        int t = 0;
        if (tid >= off) t = tmp[tid - off];
        __syncthreads();
        if (tid >= off) tmp[tid] += t;
        __syncthreads();
    }
    if (i < NN) rowstart[i] = tmp[tid] - v;  // exclusive within block
    if (tid == 255) bsum[blockIdx.x] = tmp[255];
}

// fused scan2+scan3: each block reduces its bsum prefix (196 ints) redundantly
__global__ void scan23_kernel(int* __restrict__ rowstart, const int* __restrict__ bsum) {
    __shared__ int red[4];
    int tid = threadIdx.x;
    int v = (tid < 196 && tid < (int)blockIdx.x) ? bsum[tid] : 0;
    // wave reduce
    for (int off = 32; off > 0; off >>= 1) v += __shfl_down(v, off, 64);
    if ((tid & 63) == 0) red[tid >> 6] = v;
    __syncthreads();
    int pref = red[0] + red[1] + red[2] + red[3];
    int i = blockIdx.x * 256 + tid;
    if (i < NN) rowstart[i] += pref;
    if (i == 0) rowstart[NN] = NE;
}

__global__ void scatter_kernel(const int* __restrict__ src, const int* __restrict__ dst,
                               const int* __restrict__ rowstart, int* __restrict__ cursor,
                               int* __restrict__ esrc) {
    for (int e = blockIdx.x * blockDim.x + threadIdx.x; e < NE; e += gridDim.x * blockDim.x) {
        int d = dst[e];
        int pos = rowstart[d] + atomicAdd(&cursor[d], 1);
        esrc[pos] = src[e];
    }
}

// ---------------- CSR aggregation, layer 1 -> bf16 hi/lo, K padded to 128 ----------------
__global__ __launch_bounds__(256) void agg109_bf16_kernel(const int* __restrict__ rowstart,
                                                          const int* __restrict__ esrc,
                                                          const float* __restrict__ dinv,
                                                          const float* __restrict__ x,
                                                          unsigned short* __restrict__ xa_hi,
                                                          unsigned short* __restrict__ xa_lo) {
    int wave = blockIdx.x * (blockDim.x >> 6) + (threadIdx.x >> 6);
    if (wave >= NN) return;
    int lane = threadIdx.x & 63;
    bool lo45 = lane < 45;
    long base = (long)wave * 109;
    float wd = dinv[wave];
    float acc0 = x[base + lane] * wd;
    float acc1 = lo45 ? x[base + 64 + lane] * wd : 0.0f;
    int j0 = rowstart[wave], j1 = rowstart[wave + 1];
    int j = j0;
    for (; j + 4 <= j1; j += 4) {
        int s0 = esrc[j], s1 = esrc[j + 1], s2 = esrc[j + 2], s3 = esrc[j + 3];
        float w0 = dinv[s0], w1 = dinv[s1], w2 = dinv[s2], w3 = dinv[s3];
        long b0 = (long)s0 * 109, b1 = (long)s1 * 109, b2 = (long)s2 * 109, b3 = (long)s3 * 109;
        float p0 = x[b0 + lane], p1 = x[b1 + lane], p2 = x[b2 + lane], p3 = x[b3 + lane];
        float q0 = 0, q1 = 0, q2 = 0, q3 = 0;
        if (lo45) {
            q0 = x[b0 + 64 + lane]; q1 = x[b1 + 64 + lane];
            q2 = x[b2 + 64 + lane]; q3 = x[b3 + 64 + lane];
        }
        acc0 = fmaf(p0, w0, acc0); acc0 = fmaf(p1, w1, acc0);
        acc0 = fmaf(p2, w2, acc0); acc0 = fmaf(p3, w3, acc0);
        acc1 = fmaf(q0, w0, acc1); acc1 = fmaf(q1, w1, acc1);
        acc1 = fmaf(q2, w2, acc1); acc1 = fmaf(q3, w3, acc1);
    }
    for (; j < j1; ++j) {
        int s = esrc[j];
        long sb = (long)s * 109;
        float w = dinv[s];
        acc0 = fmaf(x[sb + lane], w, acc0);
        if (lo45) acc1 = fmaf(x[sb + 64 + lane], w, acc1);
    }
    acc0 *= wd;
    float v1 = lo45 ? acc1 * wd : 0.0f;  // cols 109..127 zero-padded
    long ob = (long)wave * 128;
    unsigned short h0 = f2bf_rtn(acc0);
    xa_hi[ob + lane] = h0;
    xa_lo[ob + lane] = f2bf_rtn(acc0 - bf2f(h0));
    unsigned short h1 = f2bf_rtn(v1);
    xa_hi[ob + 64 + lane] = h1;
    xa_lo[ob + 64 + lane] = lo45 ? f2bf_rtn(v1 - bf2f(h1)) : (unsigned short)0;
}

// C = 64, epilogue: relu(v * dinv + b) -> bf16 HI ONLY (layer-3/4 input tolerates 2^-9)
__global__ __launch_bounds__(256) void agg64_relu_bf16_kernel(const int* __restrict__ rowstart,
                                                              const int* __restrict__ esrc,
                                                              const float* __restrict__ dinv,
                                                              const float* __restrict__ g,
                                                              const float* __restrict__ b,
                                                              unsigned short* __restrict__ hhi) {
    int wave = blockIdx.x * (blockDim.x >> 6) + (threadIdx.x >> 6);
    if (wave >= NN) return;
    int lane = threadIdx.x & 63;
    long base = (long)wave * 64;
    float acc = g[base + lane];
    int j0 = rowstart[wave], j1 = rowstart[wave + 1];
    int j = j0;
    for (; j + 4 <= j1; j += 4) {
        int s0 = esrc[j], s1 = esrc[j + 1], s2 = esrc[j + 2], s3 = esrc[j + 3];
        float p0 = g[(long)s0 * 64 + lane], p1 = g[(long)s1 * 64 + lane];
        float p2 = g[(long)s2 * 64 + lane], p3 = g[(long)s3 * 64 + lane];
        acc += p0 + p1 + p2 + p3;
    }
    for (; j < j1; ++j) acc += g[(long)esrc[j] * 64 + lane];
    float v = acc * dinv[wave] + b[lane];
    v = v > 0.0f ? v : 0.0f;
    hhi[base + lane] = f2bf_rtn(v);
}

// C = 64, final: split into mu / logstd halves of d_out, + bias; unroll x4
__global__ __launch_bounds__(256) void agg64_final_kernel(const int* __restrict__ rowstart,
                                                          const int* __restrict__ esrc,
                                                          const float* __restrict__ dinv,
                                                          const float* __restrict__ g,
                                                          const float* __restrict__ bmu,
                                                          const float* __restrict__ bls,
                                                          float* __restrict__ out) {
    int wave = blockIdx.x * (blockDim.x >> 6) + (threadIdx.x >> 6);
    if (wave >= NN) return;
    int lane = threadIdx.x & 63;
    long base = (long)wave * 64;
    float acc = g[base + lane];
    int j0 = rowstart[wave], j1 = rowstart[wave + 1];
    int j = j0;
    for (; j + 4 <= j1; j += 4) {
        int s0 = esrc[j], s1 = esrc[j + 1], s2 = esrc[j + 2], s3 = esrc[j + 3];
        float p0 = g[(long)s0 * 64 + lane], p1 = g[(long)s1 * 64 + lane];
        float p2 = g[(long)s2 * 64 + lane], p3 = g[(long)s3 * 64 + lane];
        acc += p0 + p1 + p2 + p3;
    }
    for (; j < j1; ++j) acc += g[(long)esrc[j] * 64 + lane];
    float v = acc * dinv[wave];
    if (lane < 32)
        out[(long)wave * 32 + lane] = v + bmu[lane];
    else
        out[(long)NN * 32 + (long)wave * 32 + (lane - 32)] = v + bls[lane - 32];
}

// ---------------- split-bf16 MFMA GEMM, 64x64 tile, reg-staged 2-phase ----------------
// C[M,N] = A[M,K] @ B^T[N,K]; K multiple of 64. 4 waves; wave w = rows w*16..+15.
// MODE 0: 3-MFMA, relu(acc+bias[col]) -> Chi/Clo.  MODE 1: 3-MFMA, acc*dinv -> Cf.
// MODE 2: A hi-only 2-MFMA (Ah*Bh + Ah*Bl), acc*dinv -> Cf.
#define LDT 72  // LDS row stride (bf16); 144 B

template <int MODE>
__global__ __launch_bounds__(256) void mfma_gemm_kernel(
    const unsigned short* __restrict__ Ahi, const unsigned short* __restrict__ Alo,
    const unsigned short* __restrict__ Bhi, const unsigned short* __restrict__ Blo,
    const float* __restrict__ bias, const float* __restrict__ dinv,
    unsigned short* __restrict__ Chi, unsigned short* __restrict__ Clo,
    float* __restrict__ Cf, int M, int N, int K, int grid_n) {
    constexpr bool ALO = (MODE != 2);
    __shared__ unsigned short As[(ALO ? 2 : 1) * 64 * LDT];  // hi at 0, lo at 64*LDT
    __shared__ unsigned short Bs[2 * 64 * LDT];
    int tid = threadIdx.x;
    int wid = tid >> 6, lane = tid & 63;
    int l15 = lane & 15, l4 = lane >> 4;

    // bijective XCD swizzle
    int T = gridDim.x;
    int xcd = blockIdx.x & 7, jj = blockIdx.x >> 3;
    int q = T >> 3, r = T & 7;
    int start = (xcd < r) ? xcd * (q + 1) : r * (q + 1) + (xcd - r) * q;
    int lin = start + jj;
    int bm = lin / grid_n, bn = lin - bm * grid_n;
    int bm0 = bm * 64, bn0 = bn * 64;

    uint4 rA[2][2], rB[2][2];  // [r2][hi/lo] staging regs
    int s_row = tid >> 3, s_slot = tid & 7;  // rows 0..31 (r2=0), 32..63 (r2=1)

    auto load_tile = [&](int kc) {
        #pragma unroll
        for (int r2 = 0; r2 < 2; ++r2) {
            int row = s_row + 32 * r2;
            int ga = bm0 + row;
            if (ga >= M) ga = M - 1;  // clamp; epilogue guards stores
            long goA = (long)ga * K + kc + s_slot * 8;
            rA[r2][0] = *(const uint4*)&Ahi[goA];
            if (ALO) rA[r2][1] = *(const uint4*)&Alo[goA];
            long goB = (long)(bn0 + row) * K + kc + s_slot * 8;
            rB[r2][0] = *(const uint4*)&Bhi[goB];
            rB[r2][1] = *(const uint4*)&Blo[goB];
        }
    };
    auto write_tile = [&]() {
        #pragma unroll
        for (int r2 = 0; r2 < 2; ++r2) {
            int row = s_row + 32 * r2;
            *(uint4*)&As[row * LDT + s_slot * 8] = rA[r2][0];
            if (ALO) *(uint4*)&As[64 * LDT + row * LDT + s_slot * 8] = rA[r2][1];
            *(uint4*)&Bs[row * LDT + s_slot * 8] = rB[r2][0];
            *(uint4*)&Bs[64 * LDT + row * LDT + s_slot * 8] = rB[r2][1];
        }
    };

    f32x4 acc[4] = {};
    load_tile(0);
    write_tile();
    __syncthreads();
    int ntiles = K >> 6;
    for (int t = 0; t < ntiles; ++t) {
        bool more = (t + 1 < ntiles);
        if (more) load_tile((t + 1) << 6);  // prefetch overlaps MFMAs below
        #pragma unroll
        for (int ks = 0; ks < 2; ++ks) {
            int koff = ks * 32 + l4 * 8;
            int ra = (wid * 16 + l15) * LDT + koff;
            short8v ah = *(const short8v*)&As[ra];
            short8v al;
            if (ALO) al = *(const short8v*)&As[64 * LDT + ra];
            #pragma unroll
            for (int n = 0; n < 4; ++n) {
                int rb = (n * 16 + l15) * LDT + koff;
                short8v bh = *(const short8v*)&Bs[rb];
                short8v bl = *(const short8v*)&Bs[64 * LDT + rb];
                acc[n] = __builtin_amdgcn_mfma_f32_16x16x32_bf16(ah, bh, acc[n], 0, 0, 0);
                if (ALO) acc[n] = __builtin_amdgcn_mfma_f32_16x16x32_bf16(al, bh, acc[n], 0, 0, 0);
                acc[n] = __builtin_amdgcn_mfma_f32_16x16x32_bf16(ah, bl, acc[n], 0, 0, 0);
            }
        }
        if (more) {
            __syncthreads();
            write_tile();
            __syncthreads();
        }
    }
    // epilogue: C/D frag mapping col=lane&15, row=(lane>>4)*4+reg
    int rbase = bm0 + wid * 16 + l4 * 4;
    #pragma unroll
    for (int q2 = 0; q2 < 4; ++q2) {
        int grow = rbase + q2;
        if (grow >= M) continue;
        float rs = (MODE != 0) ? dinv[grow] : 0.0f;
        #pragma unroll
        for (int n = 0; n < 4; ++n) {
            int gcol = bn0 + n * 16 + l15;
            float v = acc[n][q2];
            if (MODE == 0) {
                v += bias[gcol];
                v = v > 0.0f ? v : 0.0f;
                unsigned short hb = f2bf_rtn(v);
                long o = (long)grow * N + gcol;
                Chi[o] = hb;
                Clo[o] = f2bf_rtn(v - bf2f(hb));
            } else {
                Cf[(long)grow * N + gcol] = v * rs;
            }
        }
    }
}

extern "C" void kernel_launch(void* const* d_in, const int* in_sizes, int n_in,
                              void* d_out, int out_size, void* d_ws, size_t ws_size,
                              hipStream_t stream) {
    const float* x   = (const float*)d_in[0];
    const int*   ei  = (const int*)d_in[1];
    const int*   src = ei;       // edge_index[0]
    const int*   dst = ei + NE;  // edge_index[1]
    const float* W1  = (const float*)d_in[2];
    const float* b1  = (const float*)d_in[3];
    const float* W2  = (const float*)d_in[4];
    const float* b2  = (const float*)d_in[5];
    const float* Wmu = (const float*)d_in[6];
    const float* bmu = (const float*)d_in[7];
    const float* Wls = (const float*)d_in[8];
    const float* bls = (const float*)d_in[9];
    float* out = (float*)d_out;

    // ---- workspace layout ----
    char* p = (char*)d_ws;
    float* dinv   = (float*)p; p += 50048 * 4;
    int* counts   = (int*)p;   p += 50048 * 4;  // counts+cursor zeroed together in prep
    int* cursor   = (int*)p;   p += 50048 * 4;
    int* rowstart = (int*)p;   p += 50056 * 4;
    int* bsum     = (int*)p;   p += 256 * 4;
    int* esrc     = (int*)p;   p += 400000 * 4;
    unsigned short* xa_hi = (unsigned short*)p; p += 50000L * 128 * 2;  // later h2_hi
    unsigned short* xa_lo = (unsigned short*)p; p += 50000L * 128 * 2;
    unsigned short* h1_hi = (unsigned short*)p; p += 50000L * 320 * 2;
    unsigned short* h1_lo = (unsigned short*)p; p += 50000L * 320 * 2;
    float* g2             = (float*)p;          p += 50000L * 64 * 4;   // later g3
    unsigned short* w1t_hi = (unsigned short*)p; p += 320 * 128 * 2;
    unsigned short* w1t_lo = (unsigned short*)p; p += 320 * 128 * 2;
    unsigned short* w2t_hi = (unsigned short*)p; p += 64 * 320 * 2;
    unsigned short* w2t_lo = (unsigned short*)p; p += 64 * 320 * 2;
    unsigned short* wct_hi = (unsigned short*)p; p += 64 * 64 * 2;
    unsigned short* wct_lo = (unsigned short*)p; p += 64 * 64 * 2;
    unsigned short* h2_hi = xa_hi;  // xa dead after GEMM1

    const int TB = 256;
    const int NB_NODES = (NN + TB - 1) / TB;     // 196
    const int NB_AGG = (NN * 64 + TB - 1) / TB;  // 12500 (wave per node)

    // ---- prep + CSR build (5 kernels) ----
    prep_kernel<<<647, TB, 0, stream>>>(W1, W2, Wmu, Wls, counts,
                                        w1t_hi, w1t_lo, w2t_hi, w2t_lo, wct_hi, wct_lo);
    hist_kernel<<<1024, TB, 0, stream>>>(dst, counts);
    dinv_scan1_kernel<<<NB_NODES, TB, 0, stream>>>(counts, dinv, rowstart, bsum);
    scan23_kernel<<<NB_NODES, TB, 0, stream>>>(rowstart, bsum);
    scatter_kernel<<<1024, TB, 0, stream>>>(src, dst, rowstart, cursor, esrc);

    // ---- layer 1 ----
    agg109_bf16_kernel<<<NB_AGG, TB, 0, stream>>>(rowstart, esrc, dinv, x, xa_hi, xa_lo);
    mfma_gemm_kernel<0><<<782 * 5, 256, 0, stream>>>(xa_hi, xa_lo, w1t_hi, w1t_lo, b1,
                                                     nullptr, h1_hi, h1_lo, nullptr,
                                                     NN, 320, 128, 5);

    // ---- layer 2 ----
    mfma_gemm_kernel<1><<<782, 256, 0, stream>>>(h1_hi, h1_lo, w2t_hi, w2t_lo, nullptr,
                                                 dinv, nullptr, nullptr, g2,
                                                 NN, 64, 320, 1);
    agg64_relu_bf16_kernel<<<NB_AGG, TB, 0, stream>>>(rowstart, esrc, dinv, g2, b2, h2_hi);

    // ---- layers 3+4 ----
    mfma_gemm_kernel<2><<<782, 256, 0, stream>>>(h2_hi, nullptr, wct_hi, wct_lo, nullptr,
                                                 dinv, nullptr, nullptr, g2,
                                                 NN, 64, 64, 1);
    agg64_final_kernel<<<NB_AGG, TB, 0, stream>>>(rowstart, esrc, dinv, g2, bmu, bls, out);
}

// Round 8
// 212.665 us; speedup vs baseline: 1.4412x; 1.4412x over previous
//
#include <hip/hip_runtime.h>

#define NN 50000
#define NE 400000

typedef __attribute__((ext_vector_type(8))) short short8v;
typedef __attribute__((ext_vector_type(4))) float f32x4;

__device__ __forceinline__ unsigned short f2bf_rtn(float x) {
    unsigned u = __float_as_uint(x);
    unsigned r = u + 0x7FFFu + ((u >> 16) & 1u);
    return (unsigned short)(r >> 16);
}
__device__ __forceinline__ float bf2f(unsigned short h) {
    return __uint_as_float(((unsigned)h) << 16);
}

// ---------------- prep: zero counts+cursor, convert all weights ----------------
__global__ void prep_kernel(const float* __restrict__ W1, const float* __restrict__ W2,
                            const float* __restrict__ Wmu, const float* __restrict__ Wls,
                            int* __restrict__ zero_base,
                            unsigned short* __restrict__ w1t_hi, unsigned short* __restrict__ w1t_lo,
                            unsigned short* __restrict__ w2t_hi, unsigned short* __restrict__ w2t_lo,
                            unsigned short* __restrict__ wct_hi, unsigned short* __restrict__ wct_lo) {
    int b = blockIdx.x, tid = threadIdx.x;
    if (b < 391) {
        int i = b * 256 + tid;
        if (i < 100096) zero_base[i] = 0;
    } else if (b < 551) {
        int idx = (b - 391) * 256 + tid;  // < 40960
        int n = idx >> 7, k = idx & 127;
        float v = (k < 109) ? W1[(long)k * 320 + n] : 0.0f;
        unsigned short hb = f2bf_rtn(v);
        w1t_hi[idx] = hb;
        w1t_lo[idx] = f2bf_rtn(v - bf2f(hb));
    } else if (b < 631) {
        int idx = (b - 551) * 256 + tid;  // < 20480
        int n = idx / 320, k = idx - n * 320;
        float v = W2[(long)k * 64 + n];
        unsigned short hb = f2bf_rtn(v);
        w2t_hi[idx] = hb;
        w2t_lo[idx] = f2bf_rtn(v - bf2f(hb));
    } else {
        int idx = (b - 631) * 256 + tid;  // < 4096
        int n = idx >> 6, k = idx & 63;
        float v = (n < 32) ? Wmu[k * 32 + n] : Wls[k * 32 + (n - 32)];
        unsigned short hb = f2bf_rtn(v);
        wct_hi[idx] = hb;
        wct_lo[idx] = f2bf_rtn(v - bf2f(hb));
    }
}

__global__ void hist_kernel(const int* __restrict__ dst, int* __restrict__ counts) {
    for (int e = blockIdx.x * blockDim.x + threadIdx.x; e < NE; e += gridDim.x * blockDim.x)
        atomicAdd(&counts[dst[e]], 1);
}

// dinv + block-local exclusive scan (bsum = per-block total)
__global__ void dinv_scan1_kernel(const int* __restrict__ counts, float* __restrict__ dinv,
                                  int* __restrict__ rowstart, int* __restrict__ bsum) {
    __shared__ int tmp[256];
    int tid = threadIdx.x;
    int i = blockIdx.x * 256 + tid;
    int v = (i < NN) ? counts[i] : 0;
    if (i < NN) dinv[i] = rsqrtf((float)(v + 1));  // +1 self loop
    tmp[tid] = v;
    __syncthreads();
    for (int off = 1; off < 256; off <<= 1) {
        int t = 0;
        if (tid >= off) t = tmp[tid - off];
        __syncthreads();
        if (tid >= off) tmp[tid] += t;
        __syncthreads();
    }
    if (i < NN) rowstart[i] = tmp[tid] - v;  // exclusive within block
    if (tid == 255) bsum[blockIdx.x] = tmp[255];
}

// fused scan2+scan3: each block reduces its bsum prefix (196 ints) redundantly
__global__ void scan23_kernel(int* __restrict__ rowstart, const int* __restrict__ bsum) {
    __shared__ int red[4];
    int tid = threadIdx.x;
    int v = (tid < 196 && tid < (int)blockIdx.x) ? bsum[tid] : 0;
    for (int off = 32; off > 0; off >>= 1) v += __shfl_down(v, off, 64);
    if ((tid & 63) == 0) red[tid >> 6] = v;
    __syncthreads();
    int pref = red[0] + red[1] + red[2] + red[3];
    int i = blockIdx.x * 256 + tid;
    if (i < NN) rowstart[i] += pref;
    if (i == 0) rowstart[NN] = NE;
}

__global__ void scatter_kernel(const int* __restrict__ src, const int* __restrict__ dst,
                               const int* __restrict__ rowstart, int* __restrict__ cursor,
                               int* __restrict__ esrc) {
    for (int e = blockIdx.x * blockDim.x + threadIdx.x; e < NE; e += gridDim.x * blockDim.x) {
        int d = dst[e];
        int pos = rowstart[d] + atomicAdd(&cursor[d], 1);
        esrc[pos] = src[e];
    }
}

// ---------------- CSR aggregation, layer 1 -> bf16 hi/lo, K padded to 128 ----------------
__global__ __launch_bounds__(256) void agg109_bf16_kernel(const int* __restrict__ rowstart,
                                                          const int* __restrict__ esrc,
                                                          const float* __restrict__ dinv,
                                                          const float* __restrict__ x,
                                                          unsigned short* __restrict__ xa_hi,
                                                          unsigned short* __restrict__ xa_lo) {
    int wave = blockIdx.x * (blockDim.x >> 6) + (threadIdx.x >> 6);
    if (wave >= NN) return;
    int lane = threadIdx.x & 63;
    bool lo45 = lane < 45;
    long base = (long)wave * 109;
    float wd = dinv[wave];
    float acc0 = x[base + lane] * wd;
    float acc1 = lo45 ? x[base + 64 + lane] * wd : 0.0f;
    int j0 = rowstart[wave], j1 = rowstart[wave + 1];
    int j = j0;
    for (; j + 4 <= j1; j += 4) {
        int s0 = esrc[j], s1 = esrc[j + 1], s2 = esrc[j + 2], s3 = esrc[j + 3];
        float w0 = dinv[s0], w1 = dinv[s1], w2 = dinv[s2], w3 = dinv[s3];
        long b0 = (long)s0 * 109, b1 = (long)s1 * 109, b2 = (long)s2 * 109, b3 = (long)s3 * 109;
        float p0 = x[b0 + lane], p1 = x[b1 + lane], p2 = x[b2 + lane], p3 = x[b3 + lane];
        float q0 = 0, q1 = 0, q2 = 0, q3 = 0;
        if (lo45) {
            q0 = x[b0 + 64 + lane]; q1 = x[b1 + 64 + lane];
            q2 = x[b2 + 64 + lane]; q3 = x[b3 + 64 + lane];
        }
        acc0 = fmaf(p0, w0, acc0); acc0 = fmaf(p1, w1, acc0);
        acc0 = fmaf(p2, w2, acc0); acc0 = fmaf(p3, w3, acc0);
        acc1 = fmaf(q0, w0, acc1); acc1 = fmaf(q1, w1, acc1);
        acc1 = fmaf(q2, w2, acc1); acc1 = fmaf(q3, w3, acc1);
    }
    for (; j < j1; ++j) {
        int s = esrc[j];
        long sb = (long)s * 109;
        float w = dinv[s];
        acc0 = fmaf(x[sb + lane], w, acc0);
        if (lo45) acc1 = fmaf(x[sb + 64 + lane], w, acc1);
    }
    acc0 *= wd;
    float v1 = lo45 ? acc1 * wd : 0.0f;  // cols 109..127 zero-padded
    long ob = (long)wave * 128;
    unsigned short h0 = f2bf_rtn(acc0);
    xa_hi[ob + lane] = h0;
    xa_lo[ob + lane] = f2bf_rtn(acc0 - bf2f(h0));
    unsigned short h1 = f2bf_rtn(v1);
    xa_hi[ob + 64 + lane] = h1;
    xa_lo[ob + 64 + lane] = lo45 ? f2bf_rtn(v1 - bf2f(h1)) : (unsigned short)0;
}

// C = 64, epilogue: relu(v * dinv + b) -> bf16 HI ONLY (layer-3/4 input tolerates 2^-9)
__global__ __launch_bounds__(256) void agg64_relu_bf16_kernel(const int* __restrict__ rowstart,
                                                              const int* __restrict__ esrc,
                                                              const float* __restrict__ dinv,
                                                              const float* __restrict__ g,
                                                              const float* __restrict__ b,
                                                              unsigned short* __restrict__ hhi) {
    int wave = blockIdx.x * (blockDim.x >> 6) + (threadIdx.x >> 6);
    if (wave >= NN) return;
    int lane = threadIdx.x & 63;
    long base = (long)wave * 64;
    float acc = g[base + lane];
    int j0 = rowstart[wave], j1 = rowstart[wave + 1];
    int j = j0;
    for (; j + 4 <= j1; j += 4) {
        int s0 = esrc[j], s1 = esrc[j + 1], s2 = esrc[j + 2], s3 = esrc[j + 3];
        float p0 = g[(long)s0 * 64 + lane], p1 = g[(long)s1 * 64 + lane];
        float p2 = g[(long)s2 * 64 + lane], p3 = g[(long)s3 * 64 + lane];
        acc += p0 + p1 + p2 + p3;
    }
    for (; j < j1; ++j) acc += g[(long)esrc[j] * 64 + lane];
    float v = acc * dinv[wave] + b[lane];
    v = v > 0.0f ? v : 0.0f;
    hhi[base + lane] = f2bf_rtn(v);
}

// C = 64, final: split into mu / logstd halves of d_out, + bias; unroll x4
__global__ __launch_bounds__(256) void agg64_final_kernel(const int* __restrict__ rowstart,
                                                          const int* __restrict__ esrc,
                                                          const float* __restrict__ dinv,
                                                          const float* __restrict__ g,
                                                          const float* __restrict__ bmu,
                                                          const float* __restrict__ bls,
                                                          float* __restrict__ out) {
    int wave = blockIdx.x * (blockDim.x >> 6) + (threadIdx.x >> 6);
    if (wave >= NN) return;
    int lane = threadIdx.x & 63;
    long base = (long)wave * 64;
    float acc = g[base + lane];
    int j0 = rowstart[wave], j1 = rowstart[wave + 1];
    int j = j0;
    for (; j + 4 <= j1; j += 4) {
        int s0 = esrc[j], s1 = esrc[j + 1], s2 = esrc[j + 2], s3 = esrc[j + 3];
        float p0 = g[(long)s0 * 64 + lane], p1 = g[(long)s1 * 64 + lane];
        float p2 = g[(long)s2 * 64 + lane], p3 = g[(long)s3 * 64 + lane];
        acc += p0 + p1 + p2 + p3;
    }
    for (; j < j1; ++j) acc += g[(long)esrc[j] * 64 + lane];
    float v = acc * dinv[wave];
    if (lane < 32)
        out[(long)wave * 32 + lane] = v + bmu[lane];
    else
        out[(long)NN * 32 + (long)wave * 32 + (lane - 32)] = v + bls[lane - 32];
}

// ---------------- split-bf16 MFMA GEMM, 64x64 tile (round-6 proven body) ----------------
// C[M,N] = A[M,K] @ B^T[N,K]; K multiple of 64. 4 waves; wave w = rows w*16..+15.
// MODE 0: 3-MFMA, relu(acc+bias[col]) -> Chi/Clo.  MODE 1: 3-MFMA, acc*dinv -> Cf.
// MODE 2: A hi-only 2-MFMA (Ah*Bh + Ah*Bl), acc*dinv -> Cf.
#define LDT 72  // LDS row stride (bf16); 144 B -> 2-way bank aliasing only (free)

template <int MODE>
__global__ __launch_bounds__(256) void mfma_gemm_kernel(
    const unsigned short* __restrict__ Ahi, const unsigned short* __restrict__ Alo,
    const unsigned short* __restrict__ Bhi, const unsigned short* __restrict__ Blo,
    const float* __restrict__ bias, const float* __restrict__ dinv,
    unsigned short* __restrict__ Chi, unsigned short* __restrict__ Clo,
    float* __restrict__ Cf, int M, int N, int K, int grid_n) {
    constexpr bool ALO = (MODE != 2);
    __shared__ unsigned short As[(ALO ? 2 : 1) * 64 * LDT];  // hi at 0, lo at 64*LDT
    __shared__ unsigned short Bs[2 * 64 * LDT];
    int tid = threadIdx.x;
    int wid = tid >> 6, lane = tid & 63;
    int l15 = lane & 15, l4 = lane >> 4;

    // bijective XCD swizzle
    int T = gridDim.x;
    int xcd = blockIdx.x & 7, jj = blockIdx.x >> 3;
    int q = T >> 3, r = T & 7;
    int start = (xcd < r) ? xcd * (q + 1) : r * (q + 1) + (xcd - r) * q;
    int lin = start + jj;
    int bm = lin / grid_n, bn = lin - bm * grid_n;
    int bm0 = bm * 64, bn0 = bn * 64;

    f32x4 acc[4] = {};

    for (int kc = 0; kc < K; kc += 64) {
        #pragma unroll
        for (int r2 = 0; r2 < 2; ++r2) {
            int idx = tid + 256 * r2;
            int row = idx >> 3, slot = idx & 7;
            int grow = bm0 + row;
            if (grow >= M) grow = M - 1;  // clamp; epilogue guards stores
            long go = (long)grow * K + kc + slot * 8;
            *(uint4*)&As[row * LDT + slot * 8] = *(const uint4*)&Ahi[go];
            if (ALO) *(uint4*)&As[64 * LDT + row * LDT + slot * 8] = *(const uint4*)&Alo[go];
            long gob = (long)(bn0 + row) * K + kc + slot * 8;
            *(uint4*)&Bs[row * LDT + slot * 8] = *(const uint4*)&Bhi[gob];
            *(uint4*)&Bs[64 * LDT + row * LDT + slot * 8] = *(const uint4*)&Blo[gob];
        }
        __syncthreads();
        #pragma unroll
        for (int ks = 0; ks < 2; ++ks) {
            int koff = ks * 32 + l4 * 8;
            int ra = (wid * 16 + l15) * LDT + koff;
            short8v ah = *(const short8v*)&As[ra];
            short8v al;
            if (ALO) al = *(const short8v*)&As[64 * LDT + ra];
            #pragma unroll
            for (int n = 0; n < 4; ++n) {
                int rb = (n * 16 + l15) * LDT + koff;
                short8v bh = *(const short8v*)&Bs[rb];
                short8v bl = *(const short8v*)&Bs[64 * LDT + rb];
                acc[n] = __builtin_amdgcn_mfma_f32_16x16x32_bf16(ah, bh, acc[n], 0, 0, 0);
                if (ALO) acc[n] = __builtin_amdgcn_mfma_f32_16x16x32_bf16(al, bh, acc[n], 0, 0, 0);
                acc[n] = __builtin_amdgcn_mfma_f32_16x16x32_bf16(ah, bl, acc[n], 0, 0, 0);
            }
        }
        __syncthreads();
    }
    // epilogue: C/D frag mapping col=lane&15, row=(lane>>4)*4+reg
    int rbase = bm0 + wid * 16 + l4 * 4;
    #pragma unroll
    for (int q2 = 0; q2 < 4; ++q2) {
        int grow = rbase + q2;
        if (grow >= M) continue;
        float rs = (MODE != 0) ? dinv[grow] : 0.0f;
        #pragma unroll
        for (int n = 0; n < 4; ++n) {
            int gcol = bn0 + n * 16 + l15;
            float v = acc[n][q2];
            if (MODE == 0) {
                v += bias[gcol];
                v = v > 0.0f ? v : 0.0f;
                unsigned short hb = f2bf_rtn(v);
                long o = (long)grow * N + gcol;
                Chi[o] = hb;
                Clo[o] = f2bf_rtn(v - bf2f(hb));
            } else {
                Cf[(long)grow * N + gcol] = v * rs;
            }
        }
    }
}

extern "C" void kernel_launch(void* const* d_in, const int* in_sizes, int n_in,
                              void* d_out, int out_size, void* d_ws, size_t ws_size,
                              hipStream_t stream) {
    const float* x   = (const float*)d_in[0];
    const int*   ei  = (const int*)d_in[1];
    const int*   src = ei;       // edge_index[0]
    const int*   dst = ei + NE;  // edge_index[1]
    const float* W1  = (const float*)d_in[2];
    const float* b1  = (const float*)d_in[3];
    const float* W2  = (const float*)d_in[4];
    const float* b2  = (const float*)d_in[5];
    const float* Wmu = (const float*)d_in[6];
    const float* bmu = (const float*)d_in[7];
    const float* Wls = (const float*)d_in[8];
    const float* bls = (const float*)d_in[9];
    float* out = (float*)d_out;

    // ---- workspace layout ----
    char* p = (char*)d_ws;
    float* dinv   = (float*)p; p += 50048 * 4;
    int* counts   = (int*)p;   p += 50048 * 4;  // counts+cursor zeroed together in prep
    int* cursor   = (int*)p;   p += 50048 * 4;
    int* rowstart = (int*)p;   p += 50056 * 4;
    int* bsum     = (int*)p;   p += 256 * 4;
    int* esrc     = (int*)p;   p += 400000 * 4;
    unsigned short* xa_hi = (unsigned short*)p; p += 50000L * 128 * 2;  // later h2_hi
    unsigned short* xa_lo = (unsigned short*)p; p += 50000L * 128 * 2;
    unsigned short* h1_hi = (unsigned short*)p; p += 50000L * 320 * 2;
    unsigned short* h1_lo = (unsigned short*)p; p += 50000L * 320 * 2;
    float* g2             = (float*)p;          p += 50000L * 64 * 4;   // later g3
    unsigned short* w1t_hi = (unsigned short*)p; p += 320 * 128 * 2;
    unsigned short* w1t_lo = (unsigned short*)p; p += 320 * 128 * 2;
    unsigned short* w2t_hi = (unsigned short*)p; p += 64 * 320 * 2;
    unsigned short* w2t_lo = (unsigned short*)p; p += 64 * 320 * 2;
    unsigned short* wct_hi = (unsigned short*)p; p += 64 * 64 * 2;
    unsigned short* wct_lo = (unsigned short*)p; p += 64 * 64 * 2;
    unsigned short* h2_hi = xa_hi;  // xa dead after GEMM1

    const int TB = 256;
    const int NB_NODES = (NN + TB - 1) / TB;     // 196
    const int NB_AGG = (NN * 64 + TB - 1) / TB;  // 12500 (wave per node)

    // ---- prep + CSR build (5 kernels) ----
    prep_kernel<<<647, TB, 0, stream>>>(W1, W2, Wmu, Wls, counts,
                                        w1t_hi, w1t_lo, w2t_hi, w2t_lo, wct_hi, wct_lo);
    hist_kernel<<<1024, TB, 0, stream>>>(dst, counts);
    dinv_scan1_kernel<<<NB_NODES, TB, 0, stream>>>(counts, dinv, rowstart, bsum);
    scan23_kernel<<<NB_NODES, TB, 0, stream>>>(rowstart, bsum);
    scatter_kernel<<<1024, TB, 0, stream>>>(src, dst, rowstart, cursor, esrc);

    // ---- layer 1 ----
    agg109_bf16_kernel<<<NB_AGG, TB, 0, stream>>>(rowstart, esrc, dinv, x, xa_hi, xa_lo);
    mfma_gemm_kernel<0><<<782 * 5, 256, 0, stream>>>(xa_hi, xa_lo, w1t_hi, w1t_lo, b1,
                                                     nullptr, h1_hi, h1_lo, nullptr,
                                                     NN, 320, 128, 5);

    // ---- layer 2 ----
    mfma_gemm_kernel<1><<<782, 256, 0, stream>>>(h1_hi, h1_lo, w2t_hi, w2t_lo, nullptr,
                                                 dinv, nullptr, nullptr, g2,
                                                 NN, 64, 320, 1);
    agg64_relu_bf16_kernel<<<NB_AGG, TB, 0, stream>>>(rowstart, esrc, dinv, g2, b2, h2_hi);

    // ---- layers 3+4 ----
    mfma_gemm_kernel<2><<<782, 256, 0, stream>>>(h2_hi, nullptr, wct_hi, wct_lo, nullptr,
                                                 dinv, nullptr, nullptr, g2,
                                                 NN, 64, 64, 1);
    agg64_final_kernel<<<NB_AGG, TB, 0, stream>>>(rowstart, esrc, dinv, g2, bmu, bls, out);
}

// Round 9
// 206.397 us; speedup vs baseline: 1.4849x; 1.0304x over previous
//
#include <hip/hip_runtime.h>

#define NN 50000
#define NE 400000

typedef __attribute__((ext_vector_type(8))) short short8v;
typedef __attribute__((ext_vector_type(4))) float f32x4;

__device__ __forceinline__ unsigned short f2bf_rtn(float x) {
    unsigned u = __float_as_uint(x);
    unsigned r = u + 0x7FFFu + ((u >> 16) & 1u);
    return (unsigned short)(r >> 16);
}
__device__ __forceinline__ float bf2f(unsigned short h) {
    return __uint_as_float(((unsigned)h) << 16);
}

// ---------------- prep: zero counts+cursor, convert all weights ----------------
__global__ void prep_kernel(const float* __restrict__ W1, const float* __restrict__ W2,
                            const float* __restrict__ Wmu, const float* __restrict__ Wls,
                            int* __restrict__ zero_base,
                            unsigned short* __restrict__ w1t_hi, unsigned short* __restrict__ w1t_lo,
                            unsigned short* __restrict__ w2t_hi, unsigned short* __restrict__ w2t_lo,
                            unsigned short* __restrict__ wct_hi, unsigned short* __restrict__ wct_lo) {
    int b = blockIdx.x, tid = threadIdx.x;
    if (b < 391) {
        int i = b * 256 + tid;
        if (i < 100096) zero_base[i] = 0;
    } else if (b < 551) {
        int idx = (b - 391) * 256 + tid;  // < 40960
        int n = idx >> 7, k = idx & 127;
        float v = (k < 109) ? W1[(long)k * 320 + n] : 0.0f;
        unsigned short hb = f2bf_rtn(v);
        w1t_hi[idx] = hb;
        w1t_lo[idx] = f2bf_rtn(v - bf2f(hb));
    } else if (b < 631) {
        int idx = (b - 551) * 256 + tid;  // < 20480
        int n = idx / 320, k = idx - n * 320;
        float v = W2[(long)k * 64 + n];
        unsigned short hb = f2bf_rtn(v);
        w2t_hi[idx] = hb;
        w2t_lo[idx] = f2bf_rtn(v - bf2f(hb));
    } else {
        int idx = (b - 631) * 256 + tid;  // < 4096
        int n = idx >> 6, k = idx & 63;
        float v = (n < 32) ? Wmu[k * 32 + n] : Wls[k * 32 + (n - 32)];
        unsigned short hb = f2bf_rtn(v);
        wct_hi[idx] = hb;
        wct_lo[idx] = f2bf_rtn(v - bf2f(hb));
    }
}

__global__ void hist_kernel(const int* __restrict__ dst, int* __restrict__ counts) {
    for (int e = blockIdx.x * blockDim.x + threadIdx.x; e < NE; e += gridDim.x * blockDim.x)
        atomicAdd(&counts[dst[e]], 1);
}

// dinv + block-local exclusive scan (bsum = per-block total)
__global__ void dinv_scan1_kernel(const int* __restrict__ counts, float* __restrict__ dinv,
                                  int* __restrict__ rowstart, int* __restrict__ bsum) {
    __shared__ int tmp[256];
    int tid = threadIdx.x;
    int i = blockIdx.x * 256 + tid;
    int v = (i < NN) ? counts[i] : 0;
    if (i < NN) dinv[i] = rsqrtf((float)(v + 1));  // +1 self loop
    tmp[tid] = v;
    __syncthreads();
    for (int off = 1; off < 256; off <<= 1) {
        int t = 0;
        if (tid >= off) t = tmp[tid - off];
        __syncthreads();
        if (tid >= off) tmp[tid] += t;
        __syncthreads();
    }
    if (i < NN) rowstart[i] = tmp[tid] - v;  // exclusive within block
    if (tid == 255) bsum[blockIdx.x] = tmp[255];
}

// fused scan2+scan3: each block reduces its bsum prefix (196 ints) redundantly
__global__ void scan23_kernel(int* __restrict__ rowstart, const int* __restrict__ bsum) {
    __shared__ int red[4];
    int tid = threadIdx.x;
    int v = (tid < 196 && tid < (int)blockIdx.x) ? bsum[tid] : 0;
    for (int off = 32; off > 0; off >>= 1) v += __shfl_down(v, off, 64);
    if ((tid & 63) == 0) red[tid >> 6] = v;
    __syncthreads();
    int pref = red[0] + red[1] + red[2] + red[3];
    int i = blockIdx.x * 256 + tid;
    if (i < NN) rowstart[i] += pref;
    if (i == 0) rowstart[NN] = NE;
}

__global__ void scatter_kernel(const int* __restrict__ src, const int* __restrict__ dst,
                               const int* __restrict__ rowstart, int* __restrict__ cursor,
                               int* __restrict__ esrc) {
    for (int e = blockIdx.x * blockDim.x + threadIdx.x; e < NE; e += gridDim.x * blockDim.x) {
        int d = dst[e];
        int pos = rowstart[d] + atomicAdd(&cursor[d], 1);
        esrc[pos] = src[e];
    }
}

// ---------------- CSR aggregation, layer 1 -> bf16 hi/lo, K padded to 128 ----------------
// MLP depth 8: 8 independent row gathers in flight, then 4, then scalar tail
__global__ __launch_bounds__(256) void agg109_bf16_kernel(const int* __restrict__ rowstart,
                                                          const int* __restrict__ esrc,
                                                          const float* __restrict__ dinv,
                                                          const float* __restrict__ x,
                                                          unsigned short* __restrict__ xa_hi,
                                                          unsigned short* __restrict__ xa_lo) {
    int wave = blockIdx.x * (blockDim.x >> 6) + (threadIdx.x >> 6);
    if (wave >= NN) return;
    int lane = threadIdx.x & 63;
    bool lo45 = lane < 45;
    long base = (long)wave * 109;
    float wd = dinv[wave];
    float acc0 = x[base + lane] * wd;
    float acc1 = lo45 ? x[base + 64 + lane] * wd : 0.0f;
    int j0 = rowstart[wave], j1 = rowstart[wave + 1];
    int j = j0;
    for (; j + 8 <= j1; j += 8) {
        int s[8];
        float w[8], pp[8], qq[8];
        #pragma unroll
        for (int u = 0; u < 8; ++u) s[u] = esrc[j + u];
        #pragma unroll
        for (int u = 0; u < 8; ++u) w[u] = dinv[s[u]];
        #pragma unroll
        for (int u = 0; u < 8; ++u) pp[u] = x[(long)s[u] * 109 + lane];
        #pragma unroll
        for (int u = 0; u < 8; ++u) qq[u] = lo45 ? x[(long)s[u] * 109 + 64 + lane] : 0.0f;
        #pragma unroll
        for (int u = 0; u < 8; ++u) {
            acc0 = fmaf(pp[u], w[u], acc0);
            acc1 = fmaf(qq[u], w[u], acc1);
        }
    }
    for (; j + 4 <= j1; j += 4) {
        int s0 = esrc[j], s1 = esrc[j + 1], s2 = esrc[j + 2], s3 = esrc[j + 3];
        float w0 = dinv[s0], w1 = dinv[s1], w2 = dinv[s2], w3 = dinv[s3];
        long b0 = (long)s0 * 109, b1 = (long)s1 * 109, b2 = (long)s2 * 109, b3 = (long)s3 * 109;
        float p0 = x[b0 + lane], p1 = x[b1 + lane], p2 = x[b2 + lane], p3 = x[b3 + lane];
        float q0 = 0, q1 = 0, q2 = 0, q3 = 0;
        if (lo45) {
            q0 = x[b0 + 64 + lane]; q1 = x[b1 + 64 + lane];
            q2 = x[b2 + 64 + lane]; q3 = x[b3 + 64 + lane];
        }
        acc0 = fmaf(p0, w0, acc0); acc0 = fmaf(p1, w1, acc0);
        acc0 = fmaf(p2, w2, acc0); acc0 = fmaf(p3, w3, acc0);
        acc1 = fmaf(q0, w0, acc1); acc1 = fmaf(q1, w1, acc1);
        acc1 = fmaf(q2, w2, acc1); acc1 = fmaf(q3, w3, acc1);
    }
    for (; j < j1; ++j) {
        int s = esrc[j];
        long sb = (long)s * 109;
        float w = dinv[s];
        acc0 = fmaf(x[sb + lane], w, acc0);
        if (lo45) acc1 = fmaf(x[sb + 64 + lane], w, acc1);
    }
    acc0 *= wd;
    float v1 = lo45 ? acc1 * wd : 0.0f;  // cols 109..127 zero-padded
    long ob = (long)wave * 128;
    unsigned short h0 = f2bf_rtn(acc0);
    xa_hi[ob + lane] = h0;
    xa_lo[ob + lane] = f2bf_rtn(acc0 - bf2f(h0));
    unsigned short h1 = f2bf_rtn(v1);
    xa_hi[ob + 64 + lane] = h1;
    xa_lo[ob + 64 + lane] = lo45 ? f2bf_rtn(v1 - bf2f(h1)) : (unsigned short)0;
}

// C = 64, epilogue: relu(v * dinv + b) -> bf16 HI only; MLP depth 8
__global__ __launch_bounds__(256) void agg64_relu_bf16_kernel(const int* __restrict__ rowstart,
                                                              const int* __restrict__ esrc,
                                                              const float* __restrict__ dinv,
                                                              const float* __restrict__ g,
                                                              const float* __restrict__ b,
                                                              unsigned short* __restrict__ hhi) {
    int wave = blockIdx.x * (blockDim.x >> 6) + (threadIdx.x >> 6);
    if (wave >= NN) return;
    int lane = threadIdx.x & 63;
    long base = (long)wave * 64;
    float acc = g[base + lane];
    int j0 = rowstart[wave], j1 = rowstart[wave + 1];
    int j = j0;
    for (; j + 8 <= j1; j += 8) {
        int s[8];
        float pp[8];
        #pragma unroll
        for (int u = 0; u < 8; ++u) s[u] = esrc[j + u];
        #pragma unroll
        for (int u = 0; u < 8; ++u) pp[u] = g[(long)s[u] * 64 + lane];
        #pragma unroll
        for (int u = 0; u < 8; ++u) acc += pp[u];
    }
    for (; j + 4 <= j1; j += 4) {
        int s0 = esrc[j], s1 = esrc[j + 1], s2 = esrc[j + 2], s3 = esrc[j + 3];
        float p0 = g[(long)s0 * 64 + lane], p1 = g[(long)s1 * 64 + lane];
        float p2 = g[(long)s2 * 64 + lane], p3 = g[(long)s3 * 64 + lane];
        acc += p0 + p1 + p2 + p3;
    }
    for (; j < j1; ++j) acc += g[(long)esrc[j] * 64 + lane];
    float v = acc * dinv[wave] + b[lane];
    v = v > 0.0f ? v : 0.0f;
    hhi[base + lane] = f2bf_rtn(v);
}

// C = 64, final: split into mu / logstd halves of d_out, + bias; MLP depth 8
__global__ __launch_bounds__(256) void agg64_final_kernel(const int* __restrict__ rowstart,
                                                          const int* __restrict__ esrc,
                                                          const float* __restrict__ dinv,
                                                          const float* __restrict__ g,
                                                          const float* __restrict__ bmu,
                                                          const float* __restrict__ bls,
                                                          float* __restrict__ out) {
    int wave = blockIdx.x * (blockDim.x >> 6) + (threadIdx.x >> 6);
    if (wave >= NN) return;
    int lane = threadIdx.x & 63;
    long base = (long)wave * 64;
    float acc = g[base + lane];
    int j0 = rowstart[wave], j1 = rowstart[wave + 1];
    int j = j0;
    for (; j + 8 <= j1; j += 8) {
        int s[8];
        float pp[8];
        #pragma unroll
        for (int u = 0; u < 8; ++u) s[u] = esrc[j + u];
        #pragma unroll
        for (int u = 0; u < 8; ++u) pp[u] = g[(long)s[u] * 64 + lane];
        #pragma unroll
        for (int u = 0; u < 8; ++u) acc += pp[u];
    }
    for (; j + 4 <= j1; j += 4) {
        int s0 = esrc[j], s1 = esrc[j + 1], s2 = esrc[j + 2], s3 = esrc[j + 3];
        float p0 = g[(long)s0 * 64 + lane], p1 = g[(long)s1 * 64 + lane];
        float p2 = g[(long)s2 * 64 + lane], p3 = g[(long)s3 * 64 + lane];
        acc += p0 + p1 + p2 + p3;
    }
    for (; j < j1; ++j) acc += g[(long)esrc[j] * 64 + lane];
    float v = acc * dinv[wave];
    if (lane < 32)
        out[(long)wave * 32 + lane] = v + bmu[lane];
    else
        out[(long)NN * 32 + (long)wave * 32 + (lane - 32)] = v + bls[lane - 32];
}

// ---------------- split-bf16 MFMA GEMM, 64x64 tile ----------------
// C[M,N] = A[M,K] @ B^T[N,K]; K multiple of 64. 4 waves; wave w = rows w*16..+15.
// MODE 0: A hi/lo 3-MFMA, relu(acc+bias[col]) -> Chi (hi ONLY).
// MODE 2: A hi-only 2-MFMA (Ah*Bh + Ah*Bl), acc*dinv -> Cf fp32.
#define LDT 72  // LDS row stride (bf16); 144 B -> 2-way bank aliasing only (free)

template <int MODE>
__global__ __launch_bounds__(256) void mfma_gemm_kernel(
    const unsigned short* __restrict__ Ahi, const unsigned short* __restrict__ Alo,
    const unsigned short* __restrict__ Bhi, const unsigned short* __restrict__ Blo,
    const float* __restrict__ bias, const float* __restrict__ dinv,
    unsigned short* __restrict__ Chi,
    float* __restrict__ Cf, int M, int N, int K, int grid_n) {
    constexpr bool ALO = (MODE == 0);
    __shared__ unsigned short As[(ALO ? 2 : 1) * 64 * LDT];  // hi at 0, lo at 64*LDT
    __shared__ unsigned short Bs[2 * 64 * LDT];
    int tid = threadIdx.x;
    int wid = tid >> 6, lane = tid & 63;
    int l15 = lane & 15, l4 = lane >> 4;

    // bijective XCD swizzle
    int T = gridDim.x;
    int xcd = blockIdx.x & 7, jj = blockIdx.x >> 3;
    int q = T >> 3, r = T & 7;
    int start = (xcd < r) ? xcd * (q + 1) : r * (q + 1) + (xcd - r) * q;
    int lin = start + jj;
    int bm = lin / grid_n, bn = lin - bm * grid_n;
    int bm0 = bm * 64, bn0 = bn * 64;

    f32x4 acc[4] = {};

    for (int kc = 0; kc < K; kc += 64) {
        #pragma unroll
        for (int r2 = 0; r2 < 2; ++r2) {
            int idx = tid + 256 * r2;
            int row = idx >> 3, slot = idx & 7;
            int grow = bm0 + row;
            if (grow >= M) grow = M - 1;  // clamp; epilogue guards stores
            long go = (long)grow * K + kc + slot * 8;
            *(uint4*)&As[row * LDT + slot * 8] = *(const uint4*)&Ahi[go];
            if (ALO) *(uint4*)&As[64 * LDT + row * LDT + slot * 8] = *(const uint4*)&Alo[go];
            long gob = (long)(bn0 + row) * K + kc + slot * 8;
            *(uint4*)&Bs[row * LDT + slot * 8] = *(const uint4*)&Bhi[gob];
            *(uint4*)&Bs[64 * LDT + row * LDT + slot * 8] = *(const uint4*)&Blo[gob];
        }
        __syncthreads();
        #pragma unroll
        for (int ks = 0; ks < 2; ++ks) {
            int koff = ks * 32 + l4 * 8;
            int ra = (wid * 16 + l15) * LDT + koff;
            short8v ah = *(const short8v*)&As[ra];
            short8v al;
            if (ALO) al = *(const short8v*)&As[64 * LDT + ra];
            #pragma unroll
            for (int n = 0; n < 4; ++n) {
                int rb = (n * 16 + l15) * LDT + koff;
                short8v bh = *(const short8v*)&Bs[rb];
                short8v bl = *(const short8v*)&Bs[64 * LDT + rb];
                acc[n] = __builtin_amdgcn_mfma_f32_16x16x32_bf16(ah, bh, acc[n], 0, 0, 0);
                if (ALO) acc[n] = __builtin_amdgcn_mfma_f32_16x16x32_bf16(al, bh, acc[n], 0, 0, 0);
                acc[n] = __builtin_amdgcn_mfma_f32_16x16x32_bf16(ah, bl, acc[n], 0, 0, 0);
            }
        }
        __syncthreads();
    }
    // epilogue: C/D frag mapping col=lane&15, row=(lane>>4)*4+reg
    int rbase = bm0 + wid * 16 + l4 * 4;
    #pragma unroll
    for (int q2 = 0; q2 < 4; ++q2) {
        int grow = rbase + q2;
        if (grow >= M) continue;
        float rs = (MODE != 0) ? dinv[grow] : 0.0f;
        #pragma unroll
        for (int n = 0; n < 4; ++n) {
            int gcol = bn0 + n * 16 + l15;
            float v = acc[n][q2];
            if (MODE == 0) {
                v += bias[gcol];
                v = v > 0.0f ? v : 0.0f;
                Chi[(long)grow * N + gcol] = f2bf_rtn(v);
            } else {
                Cf[(long)grow * N + gcol] = v * rs;
            }
        }
    }
}

extern "C" void kernel_launch(void* const* d_in, const int* in_sizes, int n_in,
                              void* d_out, int out_size, void* d_ws, size_t ws_size,
                              hipStream_t stream) {
    const float* x   = (const float*)d_in[0];
    const int*   ei  = (const int*)d_in[1];
    const int*   src = ei;       // edge_index[0]
    const int*   dst = ei + NE;  // edge_index[1]
    const float* W1  = (const float*)d_in[2];
    const float* b1  = (const float*)d_in[3];
    const float* W2  = (const float*)d_in[4];
    const float* b2  = (const float*)d_in[5];
    const float* Wmu = (const float*)d_in[6];
    const float* bmu = (const float*)d_in[7];
    const float* Wls = (const float*)d_in[8];
    const float* bls = (const float*)d_in[9];
    float* out = (float*)d_out;

    // ---- workspace layout ----
    char* p = (char*)d_ws;
    float* dinv   = (float*)p; p += 50048 * 4;
    int* counts   = (int*)p;   p += 50048 * 4;  // counts+cursor zeroed together in prep
    int* cursor   = (int*)p;   p += 50048 * 4;
    int* rowstart = (int*)p;   p += 50056 * 4;
    int* bsum     = (int*)p;   p += 256 * 4;
    int* esrc     = (int*)p;   p += 400000 * 4;
    unsigned short* xa_hi = (unsigned short*)p; p += 50000L * 128 * 2;  // later h2_hi
    unsigned short* xa_lo = (unsigned short*)p; p += 50000L * 128 * 2;
    unsigned short* h1_hi = (unsigned short*)p; p += 50000L * 320 * 2;
    float* g2             = (float*)p;          p += 50000L * 64 * 4;   // later g3
    unsigned short* w1t_hi = (unsigned short*)p; p += 320 * 128 * 2;
    unsigned short* w1t_lo = (unsigned short*)p; p += 320 * 128 * 2;
    unsigned short* w2t_hi = (unsigned short*)p; p += 64 * 320 * 2;
    unsigned short* w2t_lo = (unsigned short*)p; p += 64 * 320 * 2;
    unsigned short* wct_hi = (unsigned short*)p; p += 64 * 64 * 2;
    unsigned short* wct_lo = (unsigned short*)p; p += 64 * 64 * 2;
    unsigned short* h2_hi = xa_hi;  // xa dead after GEMM1

    const int TB = 256;
    const int NB_NODES = (NN + TB - 1) / TB;     // 196
    const int NB_AGG = (NN * 64 + TB - 1) / TB;  // 12500 (wave per node)

    // ---- prep + CSR build (5 kernels) ----
    prep_kernel<<<647, TB, 0, stream>>>(W1, W2, Wmu, Wls, counts,
                                        w1t_hi, w1t_lo, w2t_hi, w2t_lo, wct_hi, wct_lo);
    hist_kernel<<<1024, TB, 0, stream>>>(dst, counts);
    dinv_scan1_kernel<<<NB_NODES, TB, 0, stream>>>(counts, dinv, rowstart, bsum);
    scan23_kernel<<<NB_NODES, TB, 0, stream>>>(rowstart, bsum);
    scatter_kernel<<<1024, TB, 0, stream>>>(src, dst, rowstart, cursor, esrc);

    // ---- layer 1 ----
    agg109_bf16_kernel<<<NB_AGG, TB, 0, stream>>>(rowstart, esrc, dinv, x, xa_hi, xa_lo);
    mfma_gemm_kernel<0><<<782 * 5, 256, 0, stream>>>(xa_hi, xa_lo, w1t_hi, w1t_lo, b1,
                                                     nullptr, h1_hi, nullptr,
                                                     NN, 320, 128, 5);

    // ---- layer 2 ----
    mfma_gemm_kernel<2><<<782, 256, 0, stream>>>(h1_hi, nullptr, w2t_hi, w2t_lo, nullptr,
                                                 dinv, nullptr, g2,
                                                 NN, 64, 320, 1);
    agg64_relu_bf16_kernel<<<NB_AGG, TB, 0, stream>>>(rowstart, esrc, dinv, g2, b2, h2_hi);

    // ---- layers 3+4 ----
    mfma_gemm_kernel<2><<<782, 256, 0, stream>>>(h2_hi, nullptr, wct_hi, wct_lo, nullptr,
                                                 dinv, nullptr, g2,
                                                 NN, 64, 64, 1);
    agg64_final_kernel<<<NB_AGG, TB, 0, stream>>>(rowstart, esrc, dinv, g2, bmu, bls, out);
}

// Round 10
// 201.524 us; speedup vs baseline: 1.5209x; 1.0242x over previous
//
#include <hip/hip_runtime.h>

#define NN 50000
#define NE 400000

typedef __attribute__((ext_vector_type(8))) short short8v;
typedef __attribute__((ext_vector_type(4))) float f32x4;

__device__ __forceinline__ unsigned short f2bf_rtn(float x) {
    unsigned u = __float_as_uint(x);
    unsigned r = u + 0x7FFFu + ((u >> 16) & 1u);
    return (unsigned short)(r >> 16);
}
__device__ __forceinline__ float bf2f(unsigned short h) {
    return __uint_as_float(((unsigned)h) << 16);
}

// ---------------- prep: x->packed bf16, zero counts+cursor, convert weights ----------------
// blocks [0,12500): xp; [12500,12891): zero; [12891,13051): W1; [13051,13131): W2; [13131,13147): wct
__global__ void prep_kernel(const float* __restrict__ x,
                            const float* __restrict__ W1, const float* __restrict__ W2,
                            const float* __restrict__ Wmu, const float* __restrict__ Wls,
                            unsigned* __restrict__ xp, int* __restrict__ zero_base,
                            unsigned short* __restrict__ w1t_hi, unsigned short* __restrict__ w1t_lo,
                            unsigned short* __restrict__ w2t_hi, unsigned short* __restrict__ w2t_lo,
                            unsigned short* __restrict__ wct_hi, unsigned short* __restrict__ wct_lo) {
    int b = blockIdx.x, tid = threadIdx.x;
    if (b < 12500) {
        int idx = b * 256 + tid;  // < 3,200,000
        int i = idx >> 6, c2 = (idx & 63) * 2;
        long xb = (long)i * 109;
        float v0 = (c2 < 109) ? x[xb + c2] : 0.0f;
        float v1 = (c2 + 1 < 109) ? x[xb + c2 + 1] : 0.0f;
        xp[idx] = (unsigned)f2bf_rtn(v0) | ((unsigned)f2bf_rtn(v1) << 16);
    } else if (b < 12891) {
        int i = (b - 12500) * 256 + tid;
        if (i < 100096) zero_base[i] = 0;
    } else if (b < 13051) {
        int idx = (b - 12891) * 256 + tid;  // < 40960
        int n = idx >> 7, k = idx & 127;
        float v = (k < 109) ? W1[(long)k * 320 + n] : 0.0f;
        unsigned short hb = f2bf_rtn(v);
        w1t_hi[idx] = hb;
        w1t_lo[idx] = f2bf_rtn(v - bf2f(hb));
    } else if (b < 13131) {
        int idx = (b - 13051) * 256 + tid;  // < 20480
        int n = idx / 320, k = idx - n * 320;
        float v = W2[(long)k * 64 + n];
        unsigned short hb = f2bf_rtn(v);
        w2t_hi[idx] = hb;
        w2t_lo[idx] = f2bf_rtn(v - bf2f(hb));
    } else {
        int idx = (b - 13131) * 256 + tid;  // < 4096
        int n = idx >> 6, k = idx & 63;
        float v = (n < 32) ? Wmu[k * 32 + n] : Wls[k * 32 + (n - 32)];
        unsigned short hb = f2bf_rtn(v);
        wct_hi[idx] = hb;
        wct_lo[idx] = f2bf_rtn(v - bf2f(hb));
    }
}

__global__ void hist_kernel(const int* __restrict__ dst, int* __restrict__ counts) {
    for (int e = blockIdx.x * blockDim.x + threadIdx.x; e < NE; e += gridDim.x * blockDim.x)
        atomicAdd(&counts[dst[e]], 1);
}

// dinv + block-local exclusive scan (bsum = per-block total)
__global__ void dinv_scan1_kernel(const int* __restrict__ counts, float* __restrict__ dinv,
                                  int* __restrict__ rowstart, int* __restrict__ bsum) {
    __shared__ int tmp[256];
    int tid = threadIdx.x;
    int i = blockIdx.x * 256 + tid;
    int v = (i < NN) ? counts[i] : 0;
    if (i < NN) dinv[i] = rsqrtf((float)(v + 1));  // +1 self loop
    tmp[tid] = v;
    __syncthreads();
    for (int off = 1; off < 256; off <<= 1) {
        int t = 0;
        if (tid >= off) t = tmp[tid - off];
        __syncthreads();
        if (tid >= off) tmp[tid] += t;
        __syncthreads();
    }
    if (i < NN) rowstart[i] = tmp[tid] - v;  // exclusive within block
    if (tid == 255) bsum[blockIdx.x] = tmp[255];
}

// fused scan2+scan3
__global__ void scan23_kernel(int* __restrict__ rowstart, const int* __restrict__ bsum) {
    __shared__ int red[4];
    int tid = threadIdx.x;
    int v = (tid < 196 && tid < (int)blockIdx.x) ? bsum[tid] : 0;
    for (int off = 32; off > 0; off >>= 1) v += __shfl_down(v, off, 64);
    if ((tid & 63) == 0) red[tid >> 6] = v;
    __syncthreads();
    int pref = red[0] + red[1] + red[2] + red[3];
    int i = blockIdx.x * 256 + tid;
    if (i < NN) rowstart[i] += pref;
    if (i == 0) rowstart[NN] = NE;
}

__global__ void scatter_kernel(const int* __restrict__ src, const int* __restrict__ dst,
                               const int* __restrict__ rowstart, int* __restrict__ cursor,
                               int* __restrict__ esrc) {
    for (int e = blockIdx.x * blockDim.x + threadIdx.x; e < NE; e += gridDim.x * blockDim.x) {
        int d = dst[e];
        int pos = rowstart[d] + atomicAdd(&cursor[d], 1);
        esrc[pos] = src[e];
    }
}

// ---------------- CSR aggregation, layer 1: packed-bf16 gather -> bf16 hi/lo out ----------------
// wave per node; lane c handles channels 2c,2c+1 (one u32 gather per neighbor row)
__global__ __launch_bounds__(256) void agg109_packed_kernel(const int* __restrict__ rowstart,
                                                            const int* __restrict__ esrc,
                                                            const float* __restrict__ dinv,
                                                            const unsigned* __restrict__ xp,
                                                            unsigned* __restrict__ xa_hi32,
                                                            unsigned* __restrict__ xa_lo32) {
    int wave = blockIdx.x * (blockDim.x >> 6) + (threadIdx.x >> 6);
    if (wave >= NN) return;
    int lane = threadIdx.x & 63;
    float wd = dinv[wave];
    unsigned pself = xp[(long)wave * 64 + lane];
    float acc0 = __uint_as_float(pself << 16) * wd;
    float acc1 = __uint_as_float(pself & 0xFFFF0000u) * wd;
    int j0 = rowstart[wave], j1 = rowstart[wave + 1];
    int j = j0;
    for (; j + 8 <= j1; j += 8) {
        int s[8];
        float w[8];
        unsigned pp[8];
        #pragma unroll
        for (int u = 0; u < 8; ++u) s[u] = esrc[j + u];
        #pragma unroll
        for (int u = 0; u < 8; ++u) w[u] = dinv[s[u]];
        #pragma unroll
        for (int u = 0; u < 8; ++u) pp[u] = xp[(long)s[u] * 64 + lane];
        #pragma unroll
        for (int u = 0; u < 8; ++u) {
            acc0 = fmaf(__uint_as_float(pp[u] << 16), w[u], acc0);
            acc1 = fmaf(__uint_as_float(pp[u] & 0xFFFF0000u), w[u], acc1);
        }
    }
    for (; j + 4 <= j1; j += 4) {
        int s0 = esrc[j], s1 = esrc[j + 1], s2 = esrc[j + 2], s3 = esrc[j + 3];
        float w0 = dinv[s0], w1 = dinv[s1], w2 = dinv[s2], w3 = dinv[s3];
        unsigned p0 = xp[(long)s0 * 64 + lane], p1 = xp[(long)s1 * 64 + lane];
        unsigned p2 = xp[(long)s2 * 64 + lane], p3 = xp[(long)s3 * 64 + lane];
        acc0 = fmaf(__uint_as_float(p0 << 16), w0, acc0);
        acc1 = fmaf(__uint_as_float(p0 & 0xFFFF0000u), w0, acc1);
        acc0 = fmaf(__uint_as_float(p1 << 16), w1, acc0);
        acc1 = fmaf(__uint_as_float(p1 & 0xFFFF0000u), w1, acc1);
        acc0 = fmaf(__uint_as_float(p2 << 16), w2, acc0);
        acc1 = fmaf(__uint_as_float(p2 & 0xFFFF0000u), w2, acc1);
        acc0 = fmaf(__uint_as_float(p3 << 16), w3, acc0);
        acc1 = fmaf(__uint_as_float(p3 & 0xFFFF0000u), w3, acc1);
    }
    for (; j < j1; ++j) {
        int s = esrc[j];
        float w = dinv[s];
        unsigned pv = xp[(long)s * 64 + lane];
        acc0 = fmaf(__uint_as_float(pv << 16), w, acc0);
        acc1 = fmaf(__uint_as_float(pv & 0xFFFF0000u), w, acc1);
    }
    acc0 *= wd;
    acc1 *= wd;
    unsigned short h0 = f2bf_rtn(acc0);
    unsigned short h1 = f2bf_rtn(acc1);
    long ob = (long)wave * 64 + lane;
    xa_hi32[ob] = (unsigned)h0 | ((unsigned)h1 << 16);
    unsigned short l0 = f2bf_rtn(acc0 - bf2f(h0));
    unsigned short l1 = f2bf_rtn(acc1 - bf2f(h1));
    xa_lo32[ob] = (unsigned)l0 | ((unsigned)l1 << 16);
}

// C = 64, epilogue: relu(v * dinv + b) -> bf16 HI only; MLP depth 4 (round-8 proven)
__global__ __launch_bounds__(256) void agg64_relu_bf16_kernel(const int* __restrict__ rowstart,
                                                              const int* __restrict__ esrc,
                                                              const float* __restrict__ dinv,
                                                              const float* __restrict__ g,
                                                              const float* __restrict__ b,
                                                              unsigned short* __restrict__ hhi) {
    int wave = blockIdx.x * (blockDim.x >> 6) + (threadIdx.x >> 6);
    if (wave >= NN) return;
    int lane = threadIdx.x & 63;
    long base = (long)wave * 64;
    float acc = g[base + lane];
    int j0 = rowstart[wave], j1 = rowstart[wave + 1];
    int j = j0;
    for (; j + 4 <= j1; j += 4) {
        int s0 = esrc[j], s1 = esrc[j + 1], s2 = esrc[j + 2], s3 = esrc[j + 3];
        float p0 = g[(long)s0 * 64 + lane], p1 = g[(long)s1 * 64 + lane];
        float p2 = g[(long)s2 * 64 + lane], p3 = g[(long)s3 * 64 + lane];
        acc += p0 + p1 + p2 + p3;
    }
    for (; j < j1; ++j) acc += g[(long)esrc[j] * 64 + lane];
    float v = acc * dinv[wave] + b[lane];
    v = v > 0.0f ? v : 0.0f;
    hhi[base + lane] = f2bf_rtn(v);
}

// C = 64, final: split into mu / logstd halves of d_out, + bias; MLP depth 4
__global__ __launch_bounds__(256) void agg64_final_kernel(const int* __restrict__ rowstart,
                                                          const int* __restrict__ esrc,
                                                          const float* __restrict__ dinv,
                                                          const float* __restrict__ g,
                                                          const float* __restrict__ bmu,
                                                          const float* __restrict__ bls,
                                                          float* __restrict__ out) {
    int wave = blockIdx.x * (blockDim.x >> 6) + (threadIdx.x >> 6);
    if (wave >= NN) return;
    int lane = threadIdx.x & 63;
    long base = (long)wave * 64;
    float acc = g[base + lane];
    int j0 = rowstart[wave], j1 = rowstart[wave + 1];
    int j = j0;
    for (; j + 4 <= j1; j += 4) {
        int s0 = esrc[j], s1 = esrc[j + 1], s2 = esrc[j + 2], s3 = esrc[j + 3];
        float p0 = g[(long)s0 * 64 + lane], p1 = g[(long)s1 * 64 + lane];
        float p2 = g[(long)s2 * 64 + lane], p3 = g[(long)s3 * 64 + lane];
        acc += p0 + p1 + p2 + p3;
    }
    for (; j < j1; ++j) acc += g[(long)esrc[j] * 64 + lane];
    float v = acc * dinv[wave];
    if (lane < 32)
        out[(long)wave * 32 + lane] = v + bmu[lane];
    else
        out[(long)NN * 32 + (long)wave * 32 + (lane - 32)] = v + bls[lane - 32];
}

// ---------------- split-bf16 MFMA GEMM, 64x64 tile ----------------
// MODE 0: A hi/lo 3-MFMA, relu(acc+bias[col]) -> Chi (hi only).
// MODE 2: A hi-only 2-MFMA, acc*dinv -> Cf fp32.
#define LDT 72

template <int MODE>
__global__ __launch_bounds__(256) void mfma_gemm_kernel(
    const unsigned short* __restrict__ Ahi, const unsigned short* __restrict__ Alo,
    const unsigned short* __restrict__ Bhi, const unsigned short* __restrict__ Blo,
    const float* __restrict__ bias, const float* __restrict__ dinv,
    unsigned short* __restrict__ Chi,
    float* __restrict__ Cf, int M, int N, int K, int grid_n) {
    constexpr bool ALO = (MODE == 0);
    __shared__ unsigned short As[(ALO ? 2 : 1) * 64 * LDT];
    __shared__ unsigned short Bs[2 * 64 * LDT];
    int tid = threadIdx.x;
    int wid = tid >> 6, lane = tid & 63;
    int l15 = lane & 15, l4 = lane >> 4;

    // bijective XCD swizzle
    int T = gridDim.x;
    int xcd = blockIdx.x & 7, jj = blockIdx.x >> 3;
    int q = T >> 3, r = T & 7;
    int start = (xcd < r) ? xcd * (q + 1) : r * (q + 1) + (xcd - r) * q;
    int lin = start + jj;
    int bm = lin / grid_n, bn = lin - bm * grid_n;
    int bm0 = bm * 64, bn0 = bn * 64;

    f32x4 acc[4] = {};

    for (int kc = 0; kc < K; kc += 64) {
        #pragma unroll
        for (int r2 = 0; r2 < 2; ++r2) {
            int idx = tid + 256 * r2;
            int row = idx >> 3, slot = idx & 7;
            int grow = bm0 + row;
            if (grow >= M) grow = M - 1;
            long go = (long)grow * K + kc + slot * 8;
            *(uint4*)&As[row * LDT + slot * 8] = *(const uint4*)&Ahi[go];
            if (ALO) *(uint4*)&As[64 * LDT + row * LDT + slot * 8] = *(const uint4*)&Alo[go];
            long gob = (long)(bn0 + row) * K + kc + slot * 8;
            *(uint4*)&Bs[row * LDT + slot * 8] = *(const uint4*)&Bhi[gob];
            *(uint4*)&Bs[64 * LDT + row * LDT + slot * 8] = *(const uint4*)&Blo[gob];
        }
        __syncthreads();
        #pragma unroll
        for (int ks = 0; ks < 2; ++ks) {
            int koff = ks * 32 + l4 * 8;
            int ra = (wid * 16 + l15) * LDT + koff;
            short8v ah = *(const short8v*)&As[ra];
            short8v al;
            if (ALO) al = *(const short8v*)&As[64 * LDT + ra];
            #pragma unroll
            for (int n = 0; n < 4; ++n) {
                int rb = (n * 16 + l15) * LDT + koff;
                short8v bh = *(const short8v*)&Bs[rb];
                short8v bl = *(const short8v*)&Bs[64 * LDT + rb];
                acc[n] = __builtin_amdgcn_mfma_f32_16x16x32_bf16(ah, bh, acc[n], 0, 0, 0);
                if (ALO) acc[n] = __builtin_amdgcn_mfma_f32_16x16x32_bf16(al, bh, acc[n], 0, 0, 0);
                acc[n] = __builtin_amdgcn_mfma_f32_16x16x32_bf16(ah, bl, acc[n], 0, 0, 0);
            }
        }
        __syncthreads();
    }
    int rbase = bm0 + wid * 16 + l4 * 4;
    #pragma unroll
    for (int q2 = 0; q2 < 4; ++q2) {
        int grow = rbase + q2;
        if (grow >= M) continue;
        float rs = (MODE != 0) ? dinv[grow] : 0.0f;
        #pragma unroll
        for (int n = 0; n < 4; ++n) {
            int gcol = bn0 + n * 16 + l15;
            float v = acc[n][q2];
            if (MODE == 0) {
                v += bias[gcol];
                v = v > 0.0f ? v : 0.0f;
                Chi[(long)grow * N + gcol] = f2bf_rtn(v);
            } else {
                Cf[(long)grow * N + gcol] = v * rs;
            }
        }
    }
}

extern "C" void kernel_launch(void* const* d_in, const int* in_sizes, int n_in,
                              void* d_out, int out_size, void* d_ws, size_t ws_size,
                              hipStream_t stream) {
    const float* x   = (const float*)d_in[0];
    const int*   ei  = (const int*)d_in[1];
    const int*   src = ei;       // edge_index[0]
    const int*   dst = ei + NE;  // edge_index[1]
    const float* W1  = (const float*)d_in[2];
    const float* b1  = (const float*)d_in[3];
    const float* W2  = (const float*)d_in[4];
    const float* b2  = (const float*)d_in[5];
    const float* Wmu = (const float*)d_in[6];
    const float* bmu = (const float*)d_in[7];
    const float* Wls = (const float*)d_in[8];
    const float* bls = (const float*)d_in[9];
    float* out = (float*)d_out;

    // ---- workspace layout ----
    char* p = (char*)d_ws;
    float* dinv   = (float*)p; p += 50048 * 4;
    int* counts   = (int*)p;   p += 50048 * 4;  // counts+cursor zeroed together in prep
    int* cursor   = (int*)p;   p += 50048 * 4;
    int* rowstart = (int*)p;   p += 50056 * 4;
    int* bsum     = (int*)p;   p += 256 * 4;
    int* esrc     = (int*)p;   p += 400000 * 4;
    unsigned* xp          = (unsigned*)p;       p += 50000L * 64 * 4;   // packed bf16 x
    unsigned short* xa_hi = (unsigned short*)p; p += 50000L * 128 * 2;  // later h2_hi
    unsigned short* xa_lo = (unsigned short*)p; p += 50000L * 128 * 2;
    unsigned short* h1_hi = (unsigned short*)p; p += 50000L * 320 * 2;
    float* g2             = (float*)p;          p += 50000L * 64 * 4;   // later g3
    unsigned short* w1t_hi = (unsigned short*)p; p += 320 * 128 * 2;
    unsigned short* w1t_lo = (unsigned short*)p; p += 320 * 128 * 2;
    unsigned short* w2t_hi = (unsigned short*)p; p += 64 * 320 * 2;
    unsigned short* w2t_lo = (unsigned short*)p; p += 64 * 320 * 2;
    unsigned short* wct_hi = (unsigned short*)p; p += 64 * 64 * 2;
    unsigned short* wct_lo = (unsigned short*)p; p += 64 * 64 * 2;
    unsigned short* h2_hi = xa_hi;  // xa dead after GEMM1

    const int TB = 256;
    const int NB_NODES = (NN + TB - 1) / TB;     // 196
    const int NB_AGG = (NN * 64 + TB - 1) / TB;  // 12500 (wave per node)

    // ---- prep + CSR build ----
    prep_kernel<<<13147, TB, 0, stream>>>(x, W1, W2, Wmu, Wls, xp, counts,
                                          w1t_hi, w1t_lo, w2t_hi, w2t_lo, wct_hi, wct_lo);
    hist_kernel<<<1024, TB, 0, stream>>>(dst, counts);
    dinv_scan1_kernel<<<NB_NODES, TB, 0, stream>>>(counts, dinv, rowstart, bsum);
    scan23_kernel<<<NB_NODES, TB, 0, stream>>>(rowstart, bsum);
    scatter_kernel<<<1024, TB, 0, stream>>>(src, dst, rowstart, cursor, esrc);

    // ---- layer 1 ----
    agg109_packed_kernel<<<NB_AGG, TB, 0, stream>>>(rowstart, esrc, dinv, xp,
                                                    (unsigned*)xa_hi, (unsigned*)xa_lo);
    mfma_gemm_kernel<0><<<782 * 5, 256, 0, stream>>>(xa_hi, xa_lo, w1t_hi, w1t_lo, b1,
                                                     nullptr, h1_hi, nullptr,
                                                     NN, 320, 128, 5);

    // ---- layer 2 ----
    mfma_gemm_kernel<2><<<782, 256, 0, stream>>>(h1_hi, nullptr, w2t_hi, w2t_lo, nullptr,
                                                 dinv, nullptr, g2,
                                                 NN, 64, 320, 1);
    agg64_relu_bf16_kernel<<<NB_AGG, TB, 0, stream>>>(rowstart, esrc, dinv, g2, b2, h2_hi);

    // ---- layers 3+4 ----
    mfma_gemm_kernel<2><<<782, 256, 0, stream>>>(h2_hi, nullptr, wct_hi, wct_lo, nullptr,
                                                 dinv, nullptr, g2,
                                                 NN, 64, 64, 1);
    agg64_final_kernel<<<NB_AGG, TB, 0, stream>>>(rowstart, esrc, dinv, g2, bmu, bls, out);
}

// Round 11
// 188.347 us; speedup vs baseline: 1.6273x; 1.0700x over previous
//
#include <hip/hip_runtime.h>

#define NN 50000
#define NE 400000

typedef __attribute__((ext_vector_type(8))) short short8v;
typedef __attribute__((ext_vector_type(4))) float f32x4;

__device__ __forceinline__ unsigned short f2bf_rtn(float x) {
    unsigned u = __float_as_uint(x);
    unsigned r = u + 0x7FFFu + ((u >> 16) & 1u);
    return (unsigned short)(r >> 16);
}
__device__ __forceinline__ float bf2f(unsigned short h) {
    return __uint_as_float(((unsigned)h) << 16);
}

// ---------------- prep: x->packed bf16, zero counts+cursor, convert weights ----------------
// blocks [0,12500): xp; [12500,12891): zero; [12891,13051): W1; [13051,13131): W2; [13131,13147): wct
__global__ void prep_kernel(const float* __restrict__ x,
                            const float* __restrict__ W1, const float* __restrict__ W2,
                            const float* __restrict__ Wmu, const float* __restrict__ Wls,
                            unsigned* __restrict__ xp, int* __restrict__ zero_base,
                            unsigned short* __restrict__ w1t_hi, unsigned short* __restrict__ w1t_lo,
                            unsigned short* __restrict__ w2t_hi, unsigned short* __restrict__ w2t_lo,
                            unsigned short* __restrict__ wct_hi, unsigned short* __restrict__ wct_lo) {
    int b = blockIdx.x, tid = threadIdx.x;
    if (b < 12500) {
        int idx = b * 256 + tid;  // < 3,200,000
        int i = idx >> 6, c2 = (idx & 63) * 2;
        long xb = (long)i * 109;
        float v0 = (c2 < 109) ? x[xb + c2] : 0.0f;
        float v1 = (c2 + 1 < 109) ? x[xb + c2 + 1] : 0.0f;
        xp[idx] = (unsigned)f2bf_rtn(v0) | ((unsigned)f2bf_rtn(v1) << 16);
    } else if (b < 12891) {
        int i = (b - 12500) * 256 + tid;
        if (i < 100096) zero_base[i] = 0;
    } else if (b < 13051) {
        int idx = (b - 12891) * 256 + tid;  // < 40960
        int n = idx >> 7, k = idx & 127;
        float v = (k < 109) ? W1[(long)k * 320 + n] : 0.0f;
        unsigned short hb = f2bf_rtn(v);
        w1t_hi[idx] = hb;
        w1t_lo[idx] = f2bf_rtn(v - bf2f(hb));
    } else if (b < 13131) {
        int idx = (b - 13051) * 256 + tid;  // < 20480
        int n = idx / 320, k = idx - n * 320;
        float v = W2[(long)k * 64 + n];
        unsigned short hb = f2bf_rtn(v);
        w2t_hi[idx] = hb;
        w2t_lo[idx] = f2bf_rtn(v - bf2f(hb));
    } else {
        int idx = (b - 13131) * 256 + tid;  // < 4096
        int n = idx >> 6, k = idx & 63;
        float v = (n < 32) ? Wmu[k * 32 + n] : Wls[k * 32 + (n - 32)];
        unsigned short hb = f2bf_rtn(v);
        wct_hi[idx] = hb;
        wct_lo[idx] = f2bf_rtn(v - bf2f(hb));
    }
}

__global__ void hist_kernel(const int* __restrict__ dst, int* __restrict__ counts) {
    for (int e = blockIdx.x * blockDim.x + threadIdx.x; e < NE; e += gridDim.x * blockDim.x)
        atomicAdd(&counts[dst[e]], 1);
}

// dinv + block-local exclusive scan (bsum = per-block total)
__global__ void dinv_scan1_kernel(const int* __restrict__ counts, float* __restrict__ dinv,
                                  int* __restrict__ rowstart, int* __restrict__ bsum) {
    __shared__ int tmp[256];
    int tid = threadIdx.x;
    int i = blockIdx.x * 256 + tid;
    int v = (i < NN) ? counts[i] : 0;
    if (i < NN) dinv[i] = rsqrtf((float)(v + 1));  // +1 self loop
    tmp[tid] = v;
    __syncthreads();
    for (int off = 1; off < 256; off <<= 1) {
        int t = 0;
        if (tid >= off) t = tmp[tid - off];
        __syncthreads();
        if (tid >= off) tmp[tid] += t;
        __syncthreads();
    }
    if (i < NN) rowstart[i] = tmp[tid] - v;  // exclusive within block
    if (tid == 255) bsum[blockIdx.x] = tmp[255];
}

// fused scan2+scan3
__global__ void scan23_kernel(int* __restrict__ rowstart, const int* __restrict__ bsum) {
    __shared__ int red[4];
    int tid = threadIdx.x;
    int v = (tid < 196 && tid < (int)blockIdx.x) ? bsum[tid] : 0;
    for (int off = 32; off > 0; off >>= 1) v += __shfl_down(v, off, 64);
    if ((tid & 63) == 0) red[tid >> 6] = v;
    __syncthreads();
    int pref = red[0] + red[1] + red[2] + red[3];
    int i = blockIdx.x * 256 + tid;
    if (i < NN) rowstart[i] += pref;
    if (i == 0) rowstart[NN] = NE;
}

__global__ void scatter_kernel(const int* __restrict__ src, const int* __restrict__ dst,
                               const int* __restrict__ rowstart, int* __restrict__ cursor,
                               int* __restrict__ esrc) {
    for (int e = blockIdx.x * blockDim.x + threadIdx.x; e < NE; e += gridDim.x * blockDim.x) {
        int d = dst[e];
        int pos = rowstart[d] + atomicAdd(&cursor[d], 1);
        esrc[pos] = src[e];
    }
}

// ---------------- CSR aggregation, layer 1: packed-bf16 gather -> bf16 HI out ----------------
__global__ __launch_bounds__(256) void agg109_packed_kernel(const int* __restrict__ rowstart,
                                                            const int* __restrict__ esrc,
                                                            const float* __restrict__ dinv,
                                                            const unsigned* __restrict__ xp,
                                                            unsigned* __restrict__ xa_hi32) {
    int wave = blockIdx.x * (blockDim.x >> 6) + (threadIdx.x >> 6);
    if (wave >= NN) return;
    int lane = threadIdx.x & 63;
    float wd = dinv[wave];
    unsigned pself = xp[(long)wave * 64 + lane];
    float acc0 = __uint_as_float(pself << 16) * wd;
    float acc1 = __uint_as_float(pself & 0xFFFF0000u) * wd;
    int j0 = rowstart[wave], j1 = rowstart[wave + 1];
    int j = j0;
    for (; j + 8 <= j1; j += 8) {
        int s[8];
        float w[8];
        unsigned pp[8];
        #pragma unroll
        for (int u = 0; u < 8; ++u) s[u] = esrc[j + u];
        #pragma unroll
        for (int u = 0; u < 8; ++u) w[u] = dinv[s[u]];
        #pragma unroll
        for (int u = 0; u < 8; ++u) pp[u] = xp[(long)s[u] * 64 + lane];
        #pragma unroll
        for (int u = 0; u < 8; ++u) {
            acc0 = fmaf(__uint_as_float(pp[u] << 16), w[u], acc0);
            acc1 = fmaf(__uint_as_float(pp[u] & 0xFFFF0000u), w[u], acc1);
        }
    }
    for (; j + 4 <= j1; j += 4) {
        int s0 = esrc[j], s1 = esrc[j + 1], s2 = esrc[j + 2], s3 = esrc[j + 3];
        float w0 = dinv[s0], w1 = dinv[s1], w2 = dinv[s2], w3 = dinv[s3];
        unsigned p0 = xp[(long)s0 * 64 + lane], p1 = xp[(long)s1 * 64 + lane];
        unsigned p2 = xp[(long)s2 * 64 + lane], p3 = xp[(long)s3 * 64 + lane];
        acc0 = fmaf(__uint_as_float(p0 << 16), w0, acc0);
        acc1 = fmaf(__uint_as_float(p0 & 0xFFFF0000u), w0, acc1);
        acc0 = fmaf(__uint_as_float(p1 << 16), w1, acc0);
        acc1 = fmaf(__uint_as_float(p1 & 0xFFFF0000u), w1, acc1);
        acc0 = fmaf(__uint_as_float(p2 << 16), w2, acc0);
        acc1 = fmaf(__uint_as_float(p2 & 0xFFFF0000u), w2, acc1);
        acc0 = fmaf(__uint_as_float(p3 << 16), w3, acc0);
        acc1 = fmaf(__uint_as_float(p3 & 0xFFFF0000u), w3, acc1);
    }
    for (; j < j1; ++j) {
        int s = esrc[j];
        float w = dinv[s];
        unsigned pv = xp[(long)s * 64 + lane];
        acc0 = fmaf(__uint_as_float(pv << 16), w, acc0);
        acc1 = fmaf(__uint_as_float(pv & 0xFFFF0000u), w, acc1);
    }
    acc0 *= wd;
    acc1 *= wd;
    xa_hi32[(long)wave * 64 + lane] =
        (unsigned)f2bf_rtn(acc0) | ((unsigned)f2bf_rtn(acc1) << 16);
}

// C = 64, layer 2 epilogue: relu(v * dinv + b) -> bf16 HI only; MLP depth 4
__global__ __launch_bounds__(256) void agg64_relu_bf16_kernel(const int* __restrict__ rowstart,
                                                              const int* __restrict__ esrc,
                                                              const float* __restrict__ dinv,
                                                              const float* __restrict__ g,
                                                              const float* __restrict__ b,
                                                              unsigned short* __restrict__ hhi) {
    int wave = blockIdx.x * (blockDim.x >> 6) + (threadIdx.x >> 6);
    if (wave >= NN) return;
    int lane = threadIdx.x & 63;
    long base = (long)wave * 64;
    float acc = g[base + lane];
    int j0 = rowstart[wave], j1 = rowstart[wave + 1];
    int j = j0;
    for (; j + 4 <= j1; j += 4) {
        int s0 = esrc[j], s1 = esrc[j + 1], s2 = esrc[j + 2], s3 = esrc[j + 3];
        float p0 = g[(long)s0 * 64 + lane], p1 = g[(long)s1 * 64 + lane];
        float p2 = g[(long)s2 * 64 + lane], p3 = g[(long)s3 * 64 + lane];
        acc += p0 + p1 + p2 + p3;
    }
    for (; j < j1; ++j) acc += g[(long)esrc[j] * 64 + lane];
    float v = acc * dinv[wave] + b[lane];
    v = v > 0.0f ? v : 0.0f;
    hhi[base + lane] = f2bf_rtn(v);
}

// layers 3/4 aggregation on h2 (bf16 gather, per-row dinv): a2 = agg_norm(h2) -> bf16 hi/lo
__global__ __launch_bounds__(256) void agg64b_kernel(const int* __restrict__ rowstart,
                                                     const int* __restrict__ esrc,
                                                     const float* __restrict__ dinv,
                                                     const unsigned short* __restrict__ h,
                                                     unsigned short* __restrict__ a_hi,
                                                     unsigned short* __restrict__ a_lo) {
    int wave = blockIdx.x * (blockDim.x >> 6) + (threadIdx.x >> 6);
    if (wave >= NN) return;
    int lane = threadIdx.x & 63;
    long base = (long)wave * 64;
    float wd = dinv[wave];
    float acc = bf2f(h[base + lane]) * wd;
    int j0 = rowstart[wave], j1 = rowstart[wave + 1];
    int j = j0;
    for (; j + 4 <= j1; j += 4) {
        int s0 = esrc[j], s1 = esrc[j + 1], s2 = esrc[j + 2], s3 = esrc[j + 3];
        float w0 = dinv[s0], w1 = dinv[s1], w2 = dinv[s2], w3 = dinv[s3];
        float p0 = bf2f(h[(long)s0 * 64 + lane]), p1 = bf2f(h[(long)s1 * 64 + lane]);
        float p2 = bf2f(h[(long)s2 * 64 + lane]), p3 = bf2f(h[(long)s3 * 64 + lane]);
        acc = fmaf(p0, w0, acc); acc = fmaf(p1, w1, acc);
        acc = fmaf(p2, w2, acc); acc = fmaf(p3, w3, acc);
    }
    for (; j < j1; ++j) {
        int s = esrc[j];
        acc = fmaf(bf2f(h[(long)s * 64 + lane]), dinv[s], acc);
    }
    float t = acc * wd;
    unsigned short hb = f2bf_rtn(t);
    a_hi[base + lane] = hb;
    a_lo[base + lane] = f2bf_rtn(t - bf2f(hb));
}

// ---------------- split-bf16 MFMA GEMM, 64x64 tile ----------------
// MODE 0: A hi-only, 2-MFMA (AhBh+AhBl), relu(acc+bias[col]) -> Chi bf16.
// MODE 1: A hi-only, 2-MFMA, acc*dinv[row] -> Cf fp32.
// MODE 3: A hi/lo, 3-MFMA, split epilogue: col<32 -> Cf[mu]+bias, else Cf[ls]+bias2.
#define LDT 72

template <int MODE>
__global__ __launch_bounds__(256) void mfma_gemm_kernel(
    const unsigned short* __restrict__ Ahi, const unsigned short* __restrict__ Alo,
    const unsigned short* __restrict__ Bhi, const unsigned short* __restrict__ Blo,
    const float* __restrict__ bias, const float* __restrict__ bias2,
    const float* __restrict__ dinv,
    unsigned short* __restrict__ Chi,
    float* __restrict__ Cf, int M, int N, int K, int grid_n) {
    constexpr bool ALO = (MODE == 3);
    __shared__ unsigned short As[(ALO ? 2 : 1) * 64 * LDT];
    __shared__ unsigned short Bs[2 * 64 * LDT];
    int tid = threadIdx.x;
    int wid = tid >> 6, lane = tid & 63;
    int l15 = lane & 15, l4 = lane >> 4;

    // bijective XCD swizzle
    int T = gridDim.x;
    int xcd = blockIdx.x & 7, jj = blockIdx.x >> 3;
    int q = T >> 3, r = T & 7;
    int start = (xcd < r) ? xcd * (q + 1) : r * (q + 1) + (xcd - r) * q;
    int lin = start + jj;
    int bm = lin / grid_n, bn = lin - bm * grid_n;
    int bm0 = bm * 64, bn0 = bn * 64;

    f32x4 acc[4] = {};

    for (int kc = 0; kc < K; kc += 64) {
        #pragma unroll
        for (int r2 = 0; r2 < 2; ++r2) {
            int idx = tid + 256 * r2;
            int row = idx >> 3, slot = idx & 7;
            int grow = bm0 + row;
            if (grow >= M) grow = M - 1;
            long go = (long)grow * K + kc + slot * 8;
            *(uint4*)&As[row * LDT + slot * 8] = *(const uint4*)&Ahi[go];
            if (ALO) *(uint4*)&As[64 * LDT + row * LDT + slot * 8] = *(const uint4*)&Alo[go];
            long gob = (long)(bn0 + row) * K + kc + slot * 8;
            *(uint4*)&Bs[row * LDT + slot * 8] = *(const uint4*)&Bhi[gob];
            *(uint4*)&Bs[64 * LDT + row * LDT + slot * 8] = *(const uint4*)&Blo[gob];
        }
        __syncthreads();
        #pragma unroll
        for (int ks = 0; ks < 2; ++ks) {
            int koff = ks * 32 + l4 * 8;
            int ra = (wid * 16 + l15) * LDT + koff;
            short8v ah = *(const short8v*)&As[ra];
            short8v al;
            if (ALO) al = *(const short8v*)&As[64 * LDT + ra];
            #pragma unroll
            for (int n = 0; n < 4; ++n) {
                int rb = (n * 16 + l15) * LDT + koff;
                short8v bh = *(const short8v*)&Bs[rb];
                short8v bl = *(const short8v*)&Bs[64 * LDT + rb];
                acc[n] = __builtin_amdgcn_mfma_f32_16x16x32_bf16(ah, bh, acc[n], 0, 0, 0);
                if (ALO) acc[n] = __builtin_amdgcn_mfma_f32_16x16x32_bf16(al, bh, acc[n], 0, 0, 0);
                acc[n] = __builtin_amdgcn_mfma_f32_16x16x32_bf16(ah, bl, acc[n], 0, 0, 0);
            }
        }
        __syncthreads();
    }
    // epilogue: C/D frag mapping col=lane&15, row=(lane>>4)*4+reg
    int rbase = bm0 + wid * 16 + l4 * 4;
    #pragma unroll
    for (int q2 = 0; q2 < 4; ++q2) {
        int grow = rbase + q2;
        if (grow >= M) continue;
        float rs = (MODE == 1) ? dinv[grow] : 0.0f;
        #pragma unroll
        for (int n = 0; n < 4; ++n) {
            int gcol = bn0 + n * 16 + l15;
            float v = acc[n][q2];
            if (MODE == 0) {
                v += bias[gcol];
                v = v > 0.0f ? v : 0.0f;
                Chi[(long)grow * N + gcol] = f2bf_rtn(v);
            } else if (MODE == 1) {
                Cf[(long)grow * N + gcol] = v * rs;
            } else {  // MODE 3: mu | logstd split + bias
                if (gcol < 32)
                    Cf[(long)grow * 32 + gcol] = v + bias[gcol];
                else
                    Cf[(long)NN * 32 + (long)grow * 32 + (gcol - 32)] = v + bias2[gcol - 32];
            }
        }
    }
}

extern "C" void kernel_launch(void* const* d_in, const int* in_sizes, int n_in,
                              void* d_out, int out_size, void* d_ws, size_t ws_size,
                              hipStream_t stream) {
    const float* x   = (const float*)d_in[0];
    const int*   ei  = (const int*)d_in[1];
    const int*   src = ei;       // edge_index[0]
    const int*   dst = ei + NE;  // edge_index[1]
    const float* W1  = (const float*)d_in[2];
    const float* b1  = (const float*)d_in[3];
    const float* W2  = (const float*)d_in[4];
    const float* b2  = (const float*)d_in[5];
    const float* Wmu = (const float*)d_in[6];
    const float* bmu = (const float*)d_in[7];
    const float* Wls = (const float*)d_in[8];
    const float* bls = (const float*)d_in[9];
    float* out = (float*)d_out;

    // ---- workspace layout ----
    char* p = (char*)d_ws;
    float* dinv   = (float*)p; p += 50048 * 4;
    int* counts   = (int*)p;   p += 50048 * 4;  // counts+cursor zeroed together in prep
    int* cursor   = (int*)p;   p += 50048 * 4;
    int* rowstart = (int*)p;   p += 50056 * 4;
    int* bsum     = (int*)p;   p += 256 * 4;
    int* esrc     = (int*)p;   p += 400000 * 4;
    unsigned* xp          = (unsigned*)p;       p += 50000L * 64 * 4;   // packed bf16 x
    unsigned short* xa_hi = (unsigned short*)p; p += 50000L * 128 * 2;  // later h2_hi
    unsigned short* a2_hi = (unsigned short*)p; p += 50000L * 64 * 2;
    unsigned short* a2_lo = (unsigned short*)p; p += 50000L * 64 * 2;
    unsigned short* h1_hi = (unsigned short*)p; p += 50000L * 320 * 2;
    float* g2             = (float*)p;          p += 50000L * 64 * 4;
    unsigned short* w1t_hi = (unsigned short*)p; p += 320 * 128 * 2;
    unsigned short* w1t_lo = (unsigned short*)p; p += 320 * 128 * 2;
    unsigned short* w2t_hi = (unsigned short*)p; p += 64 * 320 * 2;
    unsigned short* w2t_lo = (unsigned short*)p; p += 64 * 320 * 2;
    unsigned short* wct_hi = (unsigned short*)p; p += 64 * 64 * 2;
    unsigned short* wct_lo = (unsigned short*)p; p += 64 * 64 * 2;
    unsigned short* h2_hi = xa_hi;  // xa dead after GEMM1

    const int TB = 256;
    const int NB_NODES = (NN + TB - 1) / TB;     // 196
    const int NB_AGG = (NN * 64 + TB - 1) / TB;  // 12500 (wave per node)

    // ---- prep + CSR build ----
    prep_kernel<<<13147, TB, 0, stream>>>(x, W1, W2, Wmu, Wls, xp, counts,
                                          w1t_hi, w1t_lo, w2t_hi, w2t_lo, wct_hi, wct_lo);
    hist_kernel<<<1024, TB, 0, stream>>>(dst, counts);
    dinv_scan1_kernel<<<NB_NODES, TB, 0, stream>>>(counts, dinv, rowstart, bsum);
    scan23_kernel<<<NB_NODES, TB, 0, stream>>>(rowstart, bsum);
    scatter_kernel<<<1024, TB, 0, stream>>>(src, dst, rowstart, cursor, esrc);

    // ---- layer 1: xa = agg(x) -> bf16 hi; h1 = relu(xa@W1 + b1) -> bf16 hi ----
    agg109_packed_kernel<<<NB_AGG, TB, 0, stream>>>(rowstart, esrc, dinv, xp,
                                                    (unsigned*)xa_hi);
    mfma_gemm_kernel<0><<<782 * 5, 256, 0, stream>>>(xa_hi, nullptr, w1t_hi, w1t_lo, b1,
                                                     nullptr, nullptr, h1_hi, nullptr,
                                                     NN, 320, 128, 5);

    // ---- layer 2: g2 = (h1@W2)*dinv; h2 = relu(agg(g2) + b2) -> bf16 hi ----
    mfma_gemm_kernel<1><<<782, 256, 0, stream>>>(h1_hi, nullptr, w2t_hi, w2t_lo, nullptr,
                                                 nullptr, dinv, nullptr, g2,
                                                 NN, 64, 320, 1);
    agg64_relu_bf16_kernel<<<NB_AGG, TB, 0, stream>>>(rowstart, esrc, dinv, g2, b2, h2_hi);

    // ---- layers 3+4 (reordered): a2 = agg_norm(h2) -> bf16 hi/lo; out = a2@wct + bias ----
    agg64b_kernel<<<NB_AGG, TB, 0, stream>>>(rowstart, esrc, dinv, h2_hi, a2_hi, a2_lo);
    mfma_gemm_kernel<3><<<782, 256, 0, stream>>>(a2_hi, a2_lo, wct_hi, wct_lo, bmu,
                                                 bls, nullptr, nullptr, out,
                                                 NN, 64, 64, 1);
}

// Round 12
// 183.881 us; speedup vs baseline: 1.6668x; 1.0243x over previous
//
#include <hip/hip_runtime.h>

#define NN 50000
#define NE 400000

typedef __attribute__((ext_vector_type(8))) short short8v;
typedef __attribute__((ext_vector_type(4))) float f32x4;

__device__ __forceinline__ unsigned short f2bf_rtn(float x) {
    unsigned u = __float_as_uint(x);
    unsigned r = u + 0x7FFFu + ((u >> 16) & 1u);
    return (unsigned short)(r >> 16);
}
__device__ __forceinline__ float bf2f(unsigned short h) {
    return __uint_as_float(((unsigned)h) << 16);
}

// ---------------- prep: x->packed bf16, zero counts+cursor, convert weights ----------------
// blocks [0,12500): xp; [12500,12891): zero; [12891,13051): W1; [13051,13131): W2; [13131,13147): wct
__global__ void prep_kernel(const float* __restrict__ x,
                            const float* __restrict__ W1, const float* __restrict__ W2,
                            const float* __restrict__ Wmu, const float* __restrict__ Wls,
                            unsigned* __restrict__ xp, int* __restrict__ zero_base,
                            unsigned short* __restrict__ w1t_hi, unsigned short* __restrict__ w1t_lo,
                            unsigned short* __restrict__ w2t_hi, unsigned short* __restrict__ w2t_lo,
                            unsigned short* __restrict__ wct_hi, unsigned short* __restrict__ wct_lo) {
    int b = blockIdx.x, tid = threadIdx.x;
    if (b < 12500) {
        int idx = b * 256 + tid;  // < 3,200,000
        int i = idx >> 6, c2 = (idx & 63) * 2;
        long xb = (long)i * 109;
        float v0 = (c2 < 109) ? x[xb + c2] : 0.0f;
        float v1 = (c2 + 1 < 109) ? x[xb + c2 + 1] : 0.0f;
        xp[idx] = (unsigned)f2bf_rtn(v0) | ((unsigned)f2bf_rtn(v1) << 16);
    } else if (b < 12891) {
        int i = (b - 12500) * 256 + tid;
        if (i < 100096) zero_base[i] = 0;
    } else if (b < 13051) {
        int idx = (b - 12891) * 256 + tid;  // < 40960
        int n = idx >> 7, k = idx & 127;
        float v = (k < 109) ? W1[(long)k * 320 + n] : 0.0f;
        unsigned short hb = f2bf_rtn(v);
        w1t_hi[idx] = hb;
        w1t_lo[idx] = f2bf_rtn(v - bf2f(hb));
    } else if (b < 13131) {
        int idx = (b - 13051) * 256 + tid;  // < 20480
        int n = idx / 320, k = idx - n * 320;
        float v = W2[(long)k * 64 + n];
        unsigned short hb = f2bf_rtn(v);
        w2t_hi[idx] = hb;
        w2t_lo[idx] = f2bf_rtn(v - bf2f(hb));
    } else {
        int idx = (b - 13131) * 256 + tid;  // < 4096
        int n = idx >> 6, k = idx & 63;
        float v = (n < 32) ? Wmu[k * 32 + n] : Wls[k * 32 + (n - 32)];
        unsigned short hb = f2bf_rtn(v);
        wct_hi[idx] = hb;
        wct_lo[idx] = f2bf_rtn(v - bf2f(hb));
    }
}

__global__ void hist_kernel(const int* __restrict__ dst, int* __restrict__ counts) {
    for (int e = blockIdx.x * blockDim.x + threadIdx.x; e < NE; e += gridDim.x * blockDim.x)
        atomicAdd(&counts[dst[e]], 1);
}

// dinv + block-local exclusive scan (bsum = per-block total)
__global__ void dinv_scan1_kernel(const int* __restrict__ counts, float* __restrict__ dinv,
                                  int* __restrict__ rowstart, int* __restrict__ bsum) {
    __shared__ int tmp[256];
    int tid = threadIdx.x;
    int i = blockIdx.x * 256 + tid;
    int v = (i < NN) ? counts[i] : 0;
    if (i < NN) dinv[i] = rsqrtf((float)(v + 1));  // +1 self loop
    tmp[tid] = v;
    __syncthreads();
    for (int off = 1; off < 256; off <<= 1) {
        int t = 0;
        if (tid >= off) t = tmp[tid - off];
        __syncthreads();
        if (tid >= off) tmp[tid] += t;
        __syncthreads();
    }
    if (i < NN) rowstart[i] = tmp[tid] - v;  // exclusive within block
    if (tid == 255) bsum[blockIdx.x] = tmp[255];
}

// fused scan2+scan3
__global__ void scan23_kernel(int* __restrict__ rowstart, const int* __restrict__ bsum) {
    __shared__ int red[4];
    int tid = threadIdx.x;
    int v = (tid < 196 && tid < (int)blockIdx.x) ? bsum[tid] : 0;
    for (int off = 32; off > 0; off >>= 1) v += __shfl_down(v, off, 64);
    if ((tid & 63) == 0) red[tid >> 6] = v;
    __syncthreads();
    int pref = red[0] + red[1] + red[2] + red[3];
    int i = blockIdx.x * 256 + tid;
    if (i < NN) rowstart[i] += pref;
    if (i == 0) rowstart[NN] = NE;
}

__global__ void scatter_kernel(const int* __restrict__ src, const int* __restrict__ dst,
                               const int* __restrict__ rowstart, int* __restrict__ cursor,
                               int* __restrict__ esrc) {
    for (int e = blockIdx.x * blockDim.x + threadIdx.x; e < NE; e += gridDim.x * blockDim.x) {
        int d = dst[e];
        int pos = rowstart[d] + atomicAdd(&cursor[d], 1);
        esrc[pos] = src[e];
    }
}

// ---------------- CSR aggregation, layer 1: packed-bf16 gather -> bf16 HI out ----------------
__global__ __launch_bounds__(256) void agg109_packed_kernel(const int* __restrict__ rowstart,
                                                            const int* __restrict__ esrc,
                                                            const float* __restrict__ dinv,
                                                            const unsigned* __restrict__ xp,
                                                            unsigned* __restrict__ xa_hi32) {
    int wave = blockIdx.x * (blockDim.x >> 6) + (threadIdx.x >> 6);
    if (wave >= NN) return;
    int lane = threadIdx.x & 63;
    float wd = dinv[wave];
    unsigned pself = xp[(long)wave * 64 + lane];
    float acc0 = __uint_as_float(pself << 16) * wd;
    float acc1 = __uint_as_float(pself & 0xFFFF0000u) * wd;
    int j0 = rowstart[wave], j1 = rowstart[wave + 1];
    int j = j0;
    for (; j + 8 <= j1; j += 8) {
        int s[8];
        float w[8];
        unsigned pp[8];
        #pragma unroll
        for (int u = 0; u < 8; ++u) s[u] = esrc[j + u];
        #pragma unroll
        for (int u = 0; u < 8; ++u) w[u] = dinv[s[u]];
        #pragma unroll
        for (int u = 0; u < 8; ++u) pp[u] = xp[(long)s[u] * 64 + lane];
        #pragma unroll
        for (int u = 0; u < 8; ++u) {
            acc0 = fmaf(__uint_as_float(pp[u] << 16), w[u], acc0);
            acc1 = fmaf(__uint_as_float(pp[u] & 0xFFFF0000u), w[u], acc1);
        }
    }
    for (; j + 4 <= j1; j += 4) {
        int s0 = esrc[j], s1 = esrc[j + 1], s2 = esrc[j + 2], s3 = esrc[j + 3];
        float w0 = dinv[s0], w1 = dinv[s1], w2 = dinv[s2], w3 = dinv[s3];
        unsigned p0 = xp[(long)s0 * 64 + lane], p1 = xp[(long)s1 * 64 + lane];
        unsigned p2 = xp[(long)s2 * 64 + lane], p3 = xp[(long)s3 * 64 + lane];
        acc0 = fmaf(__uint_as_float(p0 << 16), w0, acc0);
        acc1 = fmaf(__uint_as_float(p0 & 0xFFFF0000u), w0, acc1);
        acc0 = fmaf(__uint_as_float(p1 << 16), w1, acc0);
        acc1 = fmaf(__uint_as_float(p1 & 0xFFFF0000u), w1, acc1);
        acc0 = fmaf(__uint_as_float(p2 << 16), w2, acc0);
        acc1 = fmaf(__uint_as_float(p2 & 0xFFFF0000u), w2, acc1);
        acc0 = fmaf(__uint_as_float(p3 << 16), w3, acc0);
        acc1 = fmaf(__uint_as_float(p3 & 0xFFFF0000u), w3, acc1);
    }
    for (; j < j1; ++j) {
        int s = esrc[j];
        float w = dinv[s];
        unsigned pv = xp[(long)s * 64 + lane];
        acc0 = fmaf(__uint_as_float(pv << 16), w, acc0);
        acc1 = fmaf(__uint_as_float(pv & 0xFFFF0000u), w, acc1);
    }
    acc0 *= wd;
    acc1 *= wd;
    xa_hi32[(long)wave * 64 + lane] =
        (unsigned)f2bf_rtn(acc0) | ((unsigned)f2bf_rtn(acc1) << 16);
}

// C = 64, layer 2 epilogue: relu(v + b) on bf16 gather -> bf16 HI only; MLP depth 4
// (g2b already scaled by dinv[src-row] in GEMM2 epilogue)
__global__ __launch_bounds__(256) void agg64_relu_bf16_kernel(const int* __restrict__ rowstart,
                                                              const int* __restrict__ esrc,
                                                              const float* __restrict__ dinv,
                                                              const unsigned short* __restrict__ g,
                                                              const float* __restrict__ b,
                                                              unsigned short* __restrict__ hhi) {
    int wave = blockIdx.x * (blockDim.x >> 6) + (threadIdx.x >> 6);
    if (wave >= NN) return;
    int lane = threadIdx.x & 63;
    long base = (long)wave * 64;
    float acc = bf2f(g[base + lane]);
    int j0 = rowstart[wave], j1 = rowstart[wave + 1];
    int j = j0;
    for (; j + 4 <= j1; j += 4) {
        int s0 = esrc[j], s1 = esrc[j + 1], s2 = esrc[j + 2], s3 = esrc[j + 3];
        float p0 = bf2f(g[(long)s0 * 64 + lane]), p1 = bf2f(g[(long)s1 * 64 + lane]);
        float p2 = bf2f(g[(long)s2 * 64 + lane]), p3 = bf2f(g[(long)s3 * 64 + lane]);
        acc += p0 + p1 + p2 + p3;
    }
    for (; j < j1; ++j) acc += bf2f(g[(long)esrc[j] * 64 + lane]);
    float v = acc * dinv[wave] + b[lane];
    v = v > 0.0f ? v : 0.0f;
    hhi[base + lane] = f2bf_rtn(v);
}

// layers 3/4 aggregation on h2 (bf16 gather, per-row dinv): a2 = agg_norm(h2) -> bf16 HI only
__global__ __launch_bounds__(256) void agg64b_kernel(const int* __restrict__ rowstart,
                                                     const int* __restrict__ esrc,
                                                     const float* __restrict__ dinv,
                                                     const unsigned short* __restrict__ h,
                                                     unsigned short* __restrict__ a_hi) {
    int wave = blockIdx.x * (blockDim.x >> 6) + (threadIdx.x >> 6);
    if (wave >= NN) return;
    int lane = threadIdx.x & 63;
    long base = (long)wave * 64;
    float wd = dinv[wave];
    float acc = bf2f(h[base + lane]) * wd;
    int j0 = rowstart[wave], j1 = rowstart[wave + 1];
    int j = j0;
    for (; j + 4 <= j1; j += 4) {
        int s0 = esrc[j], s1 = esrc[j + 1], s2 = esrc[j + 2], s3 = esrc[j + 3];
        float w0 = dinv[s0], w1 = dinv[s1], w2 = dinv[s2], w3 = dinv[s3];
        float p0 = bf2f(h[(long)s0 * 64 + lane]), p1 = bf2f(h[(long)s1 * 64 + lane]);
        float p2 = bf2f(h[(long)s2 * 64 + lane]), p3 = bf2f(h[(long)s3 * 64 + lane]);
        acc = fmaf(p0, w0, acc); acc = fmaf(p1, w1, acc);
        acc = fmaf(p2, w2, acc); acc = fmaf(p3, w3, acc);
    }
    for (; j < j1; ++j) {
        int s = esrc[j];
        acc = fmaf(bf2f(h[(long)s * 64 + lane]), dinv[s], acc);
    }
    a_hi[base + lane] = f2bf_rtn(acc * wd);
}

// ---------------- split-bf16 MFMA GEMM, 64x64 tile ----------------
// MODE 0: A hi-only, 2-MFMA (AhBh+AhBl), relu(acc+bias[col]) -> Chi bf16.
// MODE 1: A hi-only, 2-MFMA, acc*dinv[row] -> Chi bf16.
// MODE 3: A hi-only, 2-MFMA, split epilogue: col<32 -> Cf[mu]+bias, else Cf[ls]+bias2.
#define LDT 72

template <int MODE>
__global__ __launch_bounds__(256) void mfma_gemm_kernel(
    const unsigned short* __restrict__ Ahi,
    const unsigned short* __restrict__ Bhi, const unsigned short* __restrict__ Blo,
    const float* __restrict__ bias, const float* __restrict__ bias2,
    const float* __restrict__ dinv,
    unsigned short* __restrict__ Chi,
    float* __restrict__ Cf, int M, int N, int K, int grid_n) {
    __shared__ unsigned short As[64 * LDT];
    __shared__ unsigned short Bs[2 * 64 * LDT];
    int tid = threadIdx.x;
    int wid = tid >> 6, lane = tid & 63;
    int l15 = lane & 15, l4 = lane >> 4;

    // bijective XCD swizzle
    int T = gridDim.x;
    int xcd = blockIdx.x & 7, jj = blockIdx.x >> 3;
    int q = T >> 3, r = T & 7;
    int start = (xcd < r) ? xcd * (q + 1) : r * (q + 1) + (xcd - r) * q;
    int lin = start + jj;
    int bm = lin / grid_n, bn = lin - bm * grid_n;
    int bm0 = bm * 64, bn0 = bn * 64;

    f32x4 acc[4] = {};

    for (int kc = 0; kc < K; kc += 64) {
        #pragma unroll
        for (int r2 = 0; r2 < 2; ++r2) {
            int idx = tid + 256 * r2;
            int row = idx >> 3, slot = idx & 7;
            int grow = bm0 + row;
            if (grow >= M) grow = M - 1;
            long go = (long)grow * K + kc + slot * 8;
            *(uint4*)&As[row * LDT + slot * 8] = *(const uint4*)&Ahi[go];
            long gob = (long)(bn0 + row) * K + kc + slot * 8;
            *(uint4*)&Bs[row * LDT + slot * 8] = *(const uint4*)&Bhi[gob];
            *(uint4*)&Bs[64 * LDT + row * LDT + slot * 8] = *(const uint4*)&Blo[gob];
        }
        __syncthreads();
        #pragma unroll
        for (int ks = 0; ks < 2; ++ks) {
            int koff = ks * 32 + l4 * 8;
            int ra = (wid * 16 + l15) * LDT + koff;
            short8v ah = *(const short8v*)&As[ra];
            #pragma unroll
            for (int n = 0; n < 4; ++n) {
                int rb = (n * 16 + l15) * LDT + koff;
                short8v bh = *(const short8v*)&Bs[rb];
                short8v bl = *(const short8v*)&Bs[64 * LDT + rb];
                acc[n] = __builtin_amdgcn_mfma_f32_16x16x32_bf16(ah, bh, acc[n], 0, 0, 0);
                acc[n] = __builtin_amdgcn_mfma_f32_16x16x32_bf16(ah, bl, acc[n], 0, 0, 0);
            }
        }
        __syncthreads();
    }
    // epilogue: C/D frag mapping col=lane&15, row=(lane>>4)*4+reg
    int rbase = bm0 + wid * 16 + l4 * 4;
    #pragma unroll
    for (int q2 = 0; q2 < 4; ++q2) {
        int grow = rbase + q2;
        if (grow >= M) continue;
        float rs = (MODE == 1) ? dinv[grow] : 0.0f;
        #pragma unroll
        for (int n = 0; n < 4; ++n) {
            int gcol = bn0 + n * 16 + l15;
            float v = acc[n][q2];
            if (MODE == 0) {
                v += bias[gcol];
                v = v > 0.0f ? v : 0.0f;
                Chi[(long)grow * N + gcol] = f2bf_rtn(v);
            } else if (MODE == 1) {
                Chi[(long)grow * N + gcol] = f2bf_rtn(v * rs);
            } else {  // MODE 3: mu | logstd split + bias
                if (gcol < 32)
                    Cf[(long)grow * 32 + gcol] = v + bias[gcol];
                else
                    Cf[(long)NN * 32 + (long)grow * 32 + (gcol - 32)] = v + bias2[gcol - 32];
            }
        }
    }
}

extern "C" void kernel_launch(void* const* d_in, const int* in_sizes, int n_in,
                              void* d_out, int out_size, void* d_ws, size_t ws_size,
                              hipStream_t stream) {
    const float* x   = (const float*)d_in[0];
    const int*   ei  = (const int*)d_in[1];
    const int*   src = ei;       // edge_index[0]
    const int*   dst = ei + NE;  // edge_index[1]
    const float* W1  = (const float*)d_in[2];
    const float* b1  = (const float*)d_in[3];
    const float* W2  = (const float*)d_in[4];
    const float* b2  = (const float*)d_in[5];
    const float* Wmu = (const float*)d_in[6];
    const float* bmu = (const float*)d_in[7];
    const float* Wls = (const float*)d_in[8];
    const float* bls = (const float*)d_in[9];
    float* out = (float*)d_out;

    // ---- workspace layout ----
    char* p = (char*)d_ws;
    float* dinv   = (float*)p; p += 50048 * 4;
    int* counts   = (int*)p;   p += 50048 * 4;  // counts+cursor zeroed together in prep
    int* cursor   = (int*)p;   p += 50048 * 4;
    int* rowstart = (int*)p;   p += 50056 * 4;
    int* bsum     = (int*)p;   p += 256 * 4;
    int* esrc     = (int*)p;   p += 400000 * 4;
    unsigned* xp          = (unsigned*)p;       p += 50000L * 64 * 4;   // packed bf16 x
    unsigned short* xa_hi = (unsigned short*)p; p += 50000L * 128 * 2;  // later h2_hi
    unsigned short* a2_hi = (unsigned short*)p; p += 50000L * 64 * 2;
    unsigned short* g2b   = (unsigned short*)p; p += 50000L * 64 * 2;
    unsigned short* h1_hi = (unsigned short*)p; p += 50000L * 320 * 2;
    unsigned short* w1t_hi = (unsigned short*)p; p += 320 * 128 * 2;
    unsigned short* w1t_lo = (unsigned short*)p; p += 320 * 128 * 2;
    unsigned short* w2t_hi = (unsigned short*)p; p += 64 * 320 * 2;
    unsigned short* w2t_lo = (unsigned short*)p; p += 64 * 320 * 2;
    unsigned short* wct_hi = (unsigned short*)p; p += 64 * 64 * 2;
    unsigned short* wct_lo = (unsigned short*)p; p += 64 * 64 * 2;
    unsigned short* h2_hi = xa_hi;  // xa dead after GEMM1

    const int TB = 256;
    const int NB_NODES = (NN + TB - 1) / TB;     // 196
    const int NB_AGG = (NN * 64 + TB - 1) / TB;  // 12500 (wave per node)

    // ---- prep + CSR build ----
    prep_kernel<<<13147, TB, 0, stream>>>(x, W1, W2, Wmu, Wls, xp, counts,
                                          w1t_hi, w1t_lo, w2t_hi, w2t_lo, wct_hi, wct_lo);
    hist_kernel<<<1024, TB, 0, stream>>>(dst, counts);
    dinv_scan1_kernel<<<NB_NODES, TB, 0, stream>>>(counts, dinv, rowstart, bsum);
    scan23_kernel<<<NB_NODES, TB, 0, stream>>>(rowstart, bsum);
    scatter_kernel<<<1024, TB, 0, stream>>>(src, dst, rowstart, cursor, esrc);

    // ---- layer 1: xa = agg(x) -> bf16 hi; h1 = relu(xa@W1 + b1) -> bf16 hi ----
    agg109_packed_kernel<<<NB_AGG, TB, 0, stream>>>(rowstart, esrc, dinv, xp,
                                                    (unsigned*)xa_hi);
    mfma_gemm_kernel<0><<<782 * 5, 256, 0, stream>>>(xa_hi, w1t_hi, w1t_lo, b1,
                                                     nullptr, nullptr, h1_hi, nullptr,
                                                     NN, 320, 128, 5);

    // ---- layer 2: g2b = (h1@W2)*dinv -> bf16; h2 = relu(agg(g2b) + b2) -> bf16 hi ----
    mfma_gemm_kernel<1><<<782, 256, 0, stream>>>(h1_hi, w2t_hi, w2t_lo, nullptr,
                                                 nullptr, dinv, g2b, nullptr,
                                                 NN, 64, 320, 1);
    agg64_relu_bf16_kernel<<<NB_AGG, TB, 0, stream>>>(rowstart, esrc, dinv, g2b, b2, h2_hi);

    // ---- layers 3+4: a2 = agg_norm(h2) -> bf16 hi; out = a2@wct + bias ----
    agg64b_kernel<<<NB_AGG, TB, 0, stream>>>(rowstart, esrc, dinv, h2_hi, a2_hi);
    mfma_gemm_kernel<3><<<782, 256, 0, stream>>>(a2_hi, wct_hi, wct_lo, bmu,
                                                 bls, nullptr, nullptr, out,
                                                 NN, 64, 64, 1);
}